// Round 7
// baseline (306.887 us; speedup 1.0000x reference)
//
#include <hip/hip_runtime.h>
#include <hip/hip_bf16.h>
#include <hip/hip_fp16.h>
#include <hip/hip_fp8.h>

// GQNN: 2-layer GraphSAGE (mean aggr) + fc head. N=100k, E=3.2M, d=64/65.
// R23: L2-capacity fix. R22 post-mortem: straight-line/pipelined/no-spill and
// dur still ~55us; across 5 structural variants the constant is FETCH~112MB
// @ ~2.3TB/s => random-64B-line memory ceiling, with misses = L2 CAPACITY
// (xf8 6.4MB > 4MB per-XCD L2). Fix: split features into two 32B half-row
// arrays (3.2MB each — FITS per-XCD L2), two aggr passes per layer. Lane
// (ch2=c>>3, g=c&7) loads 16B chunk ch2 of slot g's 32B half-row (dwordx4 =
// 8 rows/instr); butterfly over g bits; lanes g<4 write 16 cols fp16 each.
// Gather loop keeps R22's no-spill idioms (intx4 AND-mask, scalar-select
// sanitize, depth-2 index prefetch). CSR/scatter/scans/gemms unchanged
// (gemm1 epilogue writes split h1f8a/h1f8b).

#define BSH 7                    // bucket shift: 128 nodes per bucket
#define NBKT 782                 // ceil(100000 / 128)
#define NBLK 512                 // binning blocks
#define PER 6250                 // edges per scatter block (E/NBLK)
#define CAP 6144                 // bucket edge capacity (mean 4096, sigma 64)
#define AB2 256                  // aggr block threads (4 waves)

typedef _Float16 half8 __attribute__((ext_vector_type(8)));
typedef float floatx4 __attribute__((ext_vector_type(4)));
typedef float floatx2 __attribute__((ext_vector_type(2)));
typedef int intx4 __attribute__((ext_vector_type(4)));

struct h4s { __half2 lo, hi; };  // 8B fp16 row chunk

// ---- fp8 (OCP e4m3) decode/encode via hw instructions ----
#if __has_builtin(__builtin_amdgcn_cvt_pk_f32_fp8)
template <bool HI>
__device__ __forceinline__ float2 f8x2_to_f2(int v) {
    floatx2 r = __builtin_amdgcn_cvt_pk_f32_fp8(v, HI);
    return make_float2(r.x, r.y);
}
#else
template <bool HI>
__device__ __forceinline__ float2 f8x2_to_f2(int v) {
    unsigned short u = HI ? (unsigned short)(((unsigned)v) >> 16)
                          : (unsigned short)(v & 0xFFFF);
    __half2_raw r = __hip_cvt_fp8x2_to_halfraw2((__hip_fp8x2_storage_t)u, __HIP_E4M3);
    return __half22float2(*(__half2*)&r);
}
#endif

#if __has_builtin(__builtin_amdgcn_cvt_pk_fp8_f32)
__device__ __forceinline__ unsigned f4_to_f8x4(float a, float b, float c, float d) {
    int lo = __builtin_amdgcn_cvt_pk_fp8_f32(a, b, 0, false);
    return (unsigned)__builtin_amdgcn_cvt_pk_fp8_f32(c, d, lo, true);
}
__device__ __forceinline__ unsigned char f_to_f8(float a) {
    return (unsigned char)(__builtin_amdgcn_cvt_pk_fp8_f32(a, a, 0, false) & 0xFF);
}
#else
__device__ __forceinline__ unsigned f4_to_f8x4(float a, float b, float c, float d) {
    unsigned lo = (unsigned)__hip_cvt_float2_to_fp8x2(make_float2(a, b), __HIP_SATFINITE, __HIP_E4M3);
    unsigned hi = (unsigned)__hip_cvt_float2_to_fp8x2(make_float2(c, d), __HIP_SATFINITE, __HIP_E4M3);
    return lo | (hi << 16);
}
__device__ __forceinline__ unsigned char f_to_f8(float a) {
    return (unsigned char)__hip_cvt_float_to_fp8(a, __HIP_SATFINITE, __HIP_E4M3);
}
#endif

// ---------------- hist + prep (fused; k-major histT) ----------------
__global__ __launch_bounds__(256) void k_histprep(
    const int* __restrict__ dst, int* __restrict__ histT, int E,
    const float* __restrict__ x, __half* __restrict__ xh,
    unsigned char* __restrict__ xf8a, unsigned char* __restrict__ xf8b, int n4,
    const float* __restrict__ W1l, const float* __restrict__ W1r,
    const float* __restrict__ W2l, const float* __restrict__ W2r,
    __half* __restrict__ wbuf1, __half* __restrict__ wbuf2) {
    if (blockIdx.x < NBLK) {
        __shared__ int h[NBKT];
        for (int i = threadIdx.x; i < NBKT; i += 256) h[i] = 0;
        __syncthreads();
        int lo = blockIdx.x * PER;
        int hi = lo + PER; if (hi > E) hi = E;
        for (int e = lo + threadIdx.x; e < hi; e += 256)
            atomicAdd(&h[dst[e] >> BSH], 1);
        __syncthreads();
        for (int k = threadIdx.x; k < NBKT; k += 256)
            histT[k * NBLK + blockIdx.x] = h[k];
    } else if (blockIdx.x < NBLK + 9) {
        int idx = (blockIdx.x - NBLK) * 256 + threadIdx.x;
        if (idx < 1280) {
            int lane = idx & 63;
            int nt = (idx >> 6) & 3;
            int kstep = idx >> 8;
            int col = nt * 16 + (lane & 15);
            int kbase = kstep * 32 + (lane >> 4) * 8;
#pragma unroll
            for (int j = 0; j < 8; ++j) {
                int k = kbase + j;
                float v;
                if (k < 64)        v = W1l[k * 64 + col];
                else if (k < 128)  v = W1r[(k - 64) * 64 + col];
                else if (k == 128) v = W1l[64 * 64 + col];
                else if (k == 129) v = W1r[64 * 64 + col];
                else v = 0.f;
                wbuf1[(size_t)idx * 8 + j] = __float2half(v);
            }
        } else if (idx < 1280 + 1024) {
            int i2 = idx - 1280;
            int lane = i2 & 63;
            int nt = (i2 >> 6) & 3;
            int kstep = i2 >> 8;
            int col = nt * 16 + (lane & 15);
            int kbase = kstep * 32 + (lane >> 4) * 8;
#pragma unroll
            for (int j = 0; j < 8; ++j) {
                int k = kbase + j;
                float v = (k < 64) ? W2l[k * 64 + col] : W2r[(k - 64) * 64 + col];
                wbuf2[(size_t)i2 * 8 + j] = __float2half(v);
            }
        }
    } else {
        int i = (blockIdx.x - NBLK - 9) * 256 + threadIdx.x;
        if (i < n4) {
            float4 v = ((const float4*)x)[i];
            ((__half2*)xh)[2 * i]     = __floats2half2_rn(v.x, v.y);
            ((__half2*)xh)[2 * i + 1] = __floats2half2_rn(v.z, v.w);
            unsigned v8 = f4_to_f8x4(v.x, v.y, v.z, v.w);
            int node = i >> 4;
            int cq = i & 15;              // which 4-col group (cols cq*4..+4)
            if (cq < 8) ((unsigned*)xf8a)[node * 8 + cq] = v8;
            else        ((unsigned*)xf8b)[node * 8 + (cq - 8)] = v8;
        }
    }
}

// ---------------- scans ----------------

__global__ __launch_bounds__(NBLK) void k_scanblk(int* __restrict__ histT,
                                                  int* __restrict__ btot) {
    __shared__ int s[NBLK];
    int k = blockIdx.x, t = threadIdx.x;
    int v = histT[k * NBLK + t];
    s[t] = v;
    __syncthreads();
    for (int off = 1; off < NBLK; off <<= 1) {
        int u = (t >= off) ? s[t - off] : 0;
        __syncthreads();
        s[t] += u;
        __syncthreads();
    }
    histT[k * NBLK + t] = s[t] - v;
    if (t == NBLK - 1) btot[k] = s[t];
}

__global__ __launch_bounds__(1024) void k_scanbkt(const int* __restrict__ btot,
                                                  int* __restrict__ bstart) {
    __shared__ int s[1024];
    int t = threadIdx.x;
    int v = (t < NBKT) ? btot[t] : 0;
    s[t] = v;
    __syncthreads();
    for (int off = 1; off < 1024; off <<= 1) {
        int u = (t >= off) ? s[t - off] : 0;
        __syncthreads();
        s[t] += u;
        __syncthreads();
    }
    if (t < NBKT) bstart[t] = s[t] - v;
    if (t == NBKT - 1) bstart[NBKT] = s[t];
}

// ---------------- scatter: LDS counting sort + quarter-wave burst writes ------
__global__ __launch_bounds__(256) void k_scatter(const int* __restrict__ src,
                                                 const int* __restrict__ dst,
                                                 const int* __restrict__ histT,
                                                 const int* __restrict__ bstart,
                                                 int* __restrict__ binned, int E) {
    __shared__ int sorted[PER];          // 25 KB
    __shared__ int lstart[NBKT + 1];
    __shared__ int cur[NBKT];
    __shared__ int gst[NBKT];
    __shared__ int tsum[256];
    int b = blockIdx.x, t = threadIdx.x;
    int base = b * PER;
    int blen = E - base; if (blen > PER) blen = PER;

    for (int k = t; k < NBKT; k += 256) lstart[k] = 0;
    __syncthreads();
    for (int e = base + t; e < base + blen; e += 256)
        atomicAdd(&lstart[dst[e] >> BSH], 1);
    __syncthreads();
    int c0 = 0;
    int i0 = t * 4;
#pragma unroll
    for (int j = 0; j < 4; ++j)
        if (i0 + j < NBKT) c0 += lstart[i0 + j];
    tsum[t] = c0;
    __syncthreads();
    for (int off = 1; off < 256; off <<= 1) {
        int u = (t >= off) ? tsum[t - off] : 0;
        __syncthreads();
        tsum[t] += u;
        __syncthreads();
    }
    int running = tsum[t] - c0;
    __syncthreads();
#pragma unroll
    for (int j = 0; j < 4; ++j) {
        int i = i0 + j;
        if (i < NBKT) {
            int v = lstart[i];
            lstart[i] = running;
            running += v;
        }
    }
    __syncthreads();
    if (t == 0) lstart[NBKT] = blen;
    for (int k = t; k < NBKT; k += 256) {
        cur[k] = lstart[k];
        gst[k] = bstart[k] + histT[k * NBLK + b];
    }
    __syncthreads();
    for (int e = base + t; e < base + blen; e += 256) {
        int d = dst[e], s = src[e];
        int pos = atomicAdd(&cur[d >> BSH], 1);
        sorted[pos] = (s << BSH) | (d & ((1 << BSH) - 1));
    }
    __syncthreads();
    int qw = t >> 4, ql = t & 15;
    for (int k = qw; k < NBKT; k += 16) {
        int st = lstart[k];
        int ln = lstart[k + 1] - st;
        int gd = gst[k];
        for (int i = ql; i < ln; i += 16)
            binned[gd + i] = sorted[st + i];
    }
}

// ---------------- CSR finalize: sort each bucket by node, in-place ----------
__global__ __launch_bounds__(512) void k_csr(int* __restrict__ binned,
                                             const int* __restrict__ bstart,
                                             int* __restrict__ nodeoff,
                                             int E, int N) {
    __shared__ int cnt[128], sarr[128], cur[128];
    __shared__ int sorted[CAP];          // 24 KB
    int k = blockIdx.x, t = threadIdx.x;
    int lo = bstart[k], hi = bstart[k + 1];
    if (t < 128) cnt[t] = 0;
    __syncthreads();
    for (int eb = lo; eb < hi; eb += 512 * 4) {
        int e0 = eb + t, e1 = e0 + 512, e2 = e0 + 1024, e3 = e0 + 1536;
        int p0 = (e0 < hi) ? binned[e0] : -1;
        int p1 = (e1 < hi) ? binned[e1] : -1;
        int p2 = (e2 < hi) ? binned[e2] : -1;
        int p3 = (e3 < hi) ? binned[e3] : -1;
        if (p0 >= 0) atomicAdd(&cnt[p0 & 127], 1);
        if (p1 >= 0) atomicAdd(&cnt[p1 & 127], 1);
        if (p2 >= 0) atomicAdd(&cnt[p2 & 127], 1);
        if (p3 >= 0) atomicAdd(&cnt[p3 & 127], 1);
    }
    __syncthreads();
    if (t < 128) sarr[t] = cnt[t];
    __syncthreads();
    for (int off = 1; off < 128; off <<= 1) {
        int u = 0;
        if (t < 128 && t >= off) u = sarr[t - off];
        __syncthreads();
        if (t < 128) sarr[t] += u;
        __syncthreads();
    }
    if (t < 128) {
        int excl = sarr[t] - cnt[t];
        cur[t] = excl;
        int node = (k << BSH) + t;
        if (node < N) nodeoff[node] = lo + excl;
    }
    if (k == NBKT - 1 && t == 0) nodeoff[N] = E;
    __syncthreads();
    for (int eb = lo; eb < hi; eb += 512 * 4) {
        int e0 = eb + t, e1 = e0 + 512, e2 = e0 + 1024, e3 = e0 + 1536;
        int p0 = (e0 < hi) ? binned[e0] : -1;
        int p1 = (e1 < hi) ? binned[e1] : -1;
        int p2 = (e2 < hi) ? binned[e2] : -1;
        int p3 = (e3 < hi) ? binned[e3] : -1;
        if (p0 >= 0) { int pos = atomicAdd(&cur[p0 & 127], 1); if (pos < CAP) sorted[pos] = p0 >> BSH; }
        if (p1 >= 0) { int pos = atomicAdd(&cur[p1 & 127], 1); if (pos < CAP) sorted[pos] = p1 >> BSH; }
        if (p2 >= 0) { int pos = atomicAdd(&cur[p2 & 127], 1); if (pos < CAP) sorted[pos] = p2 >> BSH; }
        if (p3 >= 0) { int pos = atomicAdd(&cur[p3 & 127], 1); if (pos < CAP) sorted[pos] = p3 >> BSH; }
    }
    __syncthreads();
    int len = hi - lo; if (len > CAP) len = CAP;
    for (int i = t; i < len; i += 512)
        binned[lo + i] = sorted[i];
}

// ------- aggregation over 32B half-rows (L2-resident; 4 nodes/wave) --------
// feat[node][32] fp8 (3.2MB — fits per-XCD L2). Quarter q owns one node;
// lane (ch2=c>>3, g=c&7) loads 16B chunk ch2 of neighbor slot base+g / +8
// via dwordx4 (8 rows/instr). Butterfly over g bits; lanes g<4 write the
// 16-col fp16 chunk at colbase + ch2*16 + g*4.
template <bool TAU>
__global__ __launch_bounds__(AB2, 6) void k_aggrh(
    const int* __restrict__ nbr, const int* __restrict__ nodeoff,
    const unsigned char* __restrict__ feat, const float* __restrict__ tau,
    __half* __restrict__ zm, int colbase, __half* __restrict__ mt1, int N) {
    int t = threadIdx.x;
    int lane = t & 63;
    int q = lane >> 4;
    int c = lane & 15;
    int g = c & 7;                      // neighbor-slot within a group of 8
    int ch2 = c >> 3;                   // 16B chunk index within the 32B row
    unsigned cb = (unsigned)(ch2 << 4);
    const char* fb = (const char*)feat;
    int nb = blockIdx.x << 6;           // 64 nodes per block

    for (int p = (t >> 6); p < 16; p += (AB2 / 64)) {
        int ld = (p << 2) + q;
        int node = nb + ld;
        int off0 = 0, off1 = 0;
        if (node < N) { off0 = nodeoff[node]; off1 = nodeoff[node + 1]; }
        int d = off1 - off0;
        int dm = d;
        dm = max(dm, __shfl_xor(dm, 16, 64));
        dm = max(dm, __shfl_xor(dm, 32, 64));
        float4 A0 = {0.f, 0.f, 0.f, 0.f}, A1 = A0, A2 = A0, A3 = A0;
        float sumtau = 0.f;
        int base0 = off0 + g;
        int nx0 = nbr[base0];           // binned padded: overrun reads safe
        int nx1 = nbr[base0 + 8];
        for (int base = 0; base < dm; base += 16) {
            int s0 = base + g;
            bool v0 = s0 < d, v1 = s0 + 8 < d;
            int cu0 = nx0, cu1 = nx1;
            int bn = base0 + base + 16; // prefetch next round (depth 2)
            nx0 = nbr[bn];
            nx1 = nbr[bn + 8];
            int sx0 = v0 ? cu0 : 0;     // sanitize gather row
            int sx1 = v1 ? cu1 : 0;
            intx4 r0 = *(const intx4*)(fb + (((unsigned)sx0 << 5) + cb));
            intx4 r1 = *(const intx4*)(fb + (((unsigned)sx1 << 5) + cb));
            if (TAU) {
                float ta0 = tau[sx0], ta1 = tau[sx1];
                sumtau += (v0 ? ta0 : 0.f) + (v1 ? ta1 : 0.f);
            }
            int m0 = v0 ? -1 : 0, m1 = v1 ? -1 : 0;
            r0 &= (intx4){m0, m0, m0, m0};
            r1 &= (intx4){m1, m1, m1, m1};
            {
                float2 l0 = f8x2_to_f2<false>(r0.x), h0 = f8x2_to_f2<true>(r0.x);
                float2 l1 = f8x2_to_f2<false>(r0.y), h1v = f8x2_to_f2<true>(r0.y);
                float2 l2 = f8x2_to_f2<false>(r0.z), h2v = f8x2_to_f2<true>(r0.z);
                float2 l3 = f8x2_to_f2<false>(r0.w), h3v = f8x2_to_f2<true>(r0.w);
                A0.x += l0.x; A0.y += l0.y; A0.z += h0.x; A0.w += h0.y;
                A1.x += l1.x; A1.y += l1.y; A1.z += h1v.x; A1.w += h1v.y;
                A2.x += l2.x; A2.y += l2.y; A2.z += h2v.x; A2.w += h2v.y;
                A3.x += l3.x; A3.y += l3.y; A3.z += h3v.x; A3.w += h3v.y;
            }
            {
                float2 l0 = f8x2_to_f2<false>(r1.x), h0 = f8x2_to_f2<true>(r1.x);
                float2 l1 = f8x2_to_f2<false>(r1.y), h1v = f8x2_to_f2<true>(r1.y);
                float2 l2 = f8x2_to_f2<false>(r1.z), h2v = f8x2_to_f2<true>(r1.z);
                float2 l3 = f8x2_to_f2<false>(r1.w), h3v = f8x2_to_f2<true>(r1.w);
                A0.x += l0.x; A0.y += l0.y; A0.z += h0.x; A0.w += h0.y;
                A1.x += l1.x; A1.y += l1.y; A1.z += h1v.x; A1.w += h1v.y;
                A2.x += l2.x; A2.y += l2.y; A2.z += h2v.x; A2.w += h2v.y;
                A3.x += l3.x; A3.y += l3.y; A3.z += h3v.x; A3.w += h3v.y;
            }
        }
        // butterfly over g bits (1,2,4): stays within the 8-lane g-group of
        // each ch2 half; every lane ends with the chunk's full sum.
#pragma unroll
        for (int off = 1; off <= 4; off <<= 1) {
            A0.x += __shfl_xor(A0.x, off, 64); A0.y += __shfl_xor(A0.y, off, 64);
            A0.z += __shfl_xor(A0.z, off, 64); A0.w += __shfl_xor(A0.w, off, 64);
            A1.x += __shfl_xor(A1.x, off, 64); A1.y += __shfl_xor(A1.y, off, 64);
            A1.z += __shfl_xor(A1.z, off, 64); A1.w += __shfl_xor(A1.w, off, 64);
            A2.x += __shfl_xor(A2.x, off, 64); A2.y += __shfl_xor(A2.y, off, 64);
            A2.z += __shfl_xor(A2.z, off, 64); A2.w += __shfl_xor(A2.w, off, 64);
            A3.x += __shfl_xor(A3.x, off, 64); A3.y += __shfl_xor(A3.y, off, 64);
            A3.z += __shfl_xor(A3.z, off, 64); A3.w += __shfl_xor(A3.w, off, 64);
            if (TAU) sumtau += __shfl_xor(sumtau, off, 64);
        }
        float inv = 1.f / fmaxf((float)d, 1.f);
        if (node < N && g < 4) {
            // lane (ch2,g) writes dword g of chunk ch2: cols colbase+ch2*16+g*4
            float4 Aw = (g == 0) ? A0 : ((g == 1) ? A1 : ((g == 2) ? A2 : A3));
            h4s o;
            o.lo = __floats2half2_rn(Aw.x * inv, Aw.y * inv);
            o.hi = __floats2half2_rn(Aw.z * inv, Aw.w * inv);
            *(h4s*)(zm + (size_t)node * 64 + colbase + (ch2 << 4) + (g << 2)) = o;
        }
        if (TAU && node < N && c == 0) mt1[node] = __float2half(sumtau * inv);
    }
}

// ---------------- MFMA GEMM kernels ----------------

__global__ __launch_bounds__(256) void k_gemm1(
    const __half* __restrict__ zm1, const __half* __restrict__ mt1,
    const __half* __restrict__ xh, const float* __restrict__ tau,
    const __half* __restrict__ wbuf1, const float* __restrict__ b1l,
    __half* __restrict__ h1, unsigned char* __restrict__ h1f8a,
    unsigned char* __restrict__ h1f8b, int ntiles) {
    int tile = blockIdx.x * 4 + (threadIdx.x >> 6);
    if (tile >= ntiles) return;
    int lane = threadIdx.x & 63;
    int sub = lane & 15;
    int quad = lane >> 4;
    int row = tile * 16 + sub;

    floatx4 acc0 = {0.f, 0.f, 0.f, 0.f};
    floatx4 acc1 = {0.f, 0.f, 0.f, 0.f};
    floatx4 acc2 = {0.f, 0.f, 0.f, 0.f};
    floatx4 acc3 = {0.f, 0.f, 0.f, 0.f};

    const _Float16* zrow = (const _Float16*)zm1 + (size_t)row * 64 + quad * 8;
    const _Float16* xrow = (const _Float16*)xh + (size_t)row * 64 + quad * 8;
    const _Float16* wb = (const _Float16*)wbuf1 + (size_t)lane * 8;

    half8 amat[5];
    amat[0] = *(const half8*)(zrow);
    amat[1] = *(const half8*)(zrow + 32);
    amat[2] = *(const half8*)(xrow);
    amat[3] = *(const half8*)(xrow + 32);
    half8 a4 = {0, 0, 0, 0, 0, 0, 0, 0};
    if (quad == 0) {
        a4[0] = ((const _Float16*)mt1)[row];
        a4[1] = (_Float16)tau[row];
    }
    amat[4] = a4;

#pragma unroll
    for (int ks = 0; ks < 5; ++ks) {
        half8 a = amat[ks];
        half8 b0 = *(const half8*)(wb + (size_t)(ks * 4 + 0) * 512);
        half8 b1 = *(const half8*)(wb + (size_t)(ks * 4 + 1) * 512);
        half8 b2 = *(const half8*)(wb + (size_t)(ks * 4 + 2) * 512);
        half8 b3 = *(const half8*)(wb + (size_t)(ks * 4 + 3) * 512);
        acc0 = __builtin_amdgcn_mfma_f32_16x16x32_f16(a, b0, acc0, 0, 0, 0);
        acc1 = __builtin_amdgcn_mfma_f32_16x16x32_f16(a, b1, acc1, 0, 0, 0);
        acc2 = __builtin_amdgcn_mfma_f32_16x16x32_f16(a, b2, acc2, 0, 0, 0);
        acc3 = __builtin_amdgcn_mfma_f32_16x16x32_f16(a, b3, acc3, 0, 0, 0);
    }
    float bv0 = b1l[sub], bv1 = b1l[16 + sub], bv2 = b1l[32 + sub], bv3 = b1l[48 + sub];
#pragma unroll
    for (int reg = 0; reg < 4; ++reg) {
        int r = quad * 4 + reg;
        float v0 = fmaxf(acc0[reg] + bv0, 0.f);
        float v1 = fmaxf(acc1[reg] + bv1, 0.f);
        float v2 = fmaxf(acc2[reg] + bv2, 0.f);
        float v3 = fmaxf(acc3[reg] + bv3, 0.f);
        __half* orow = h1 + (size_t)(tile * 16 + r) * 64;
        orow[sub]      = __float2half(v0);
        orow[16 + sub] = __float2half(v1);
        orow[32 + sub] = __float2half(v2);
        orow[48 + sub] = __float2half(v3);
        unsigned char* oa = h1f8a + (size_t)(tile * 16 + r) * 32;
        unsigned char* ob = h1f8b + (size_t)(tile * 16 + r) * 32;
        oa[sub]      = f_to_f8(v0);
        oa[16 + sub] = f_to_f8(v1);
        ob[sub]      = f_to_f8(v2);
        ob[16 + sub] = f_to_f8(v3);
    }
}

__global__ __launch_bounds__(256) void k_gemm2(
    const __half* __restrict__ zm2, const __half* __restrict__ h1,
    const __half* __restrict__ wbuf2, const float* __restrict__ b2l,
    const float* __restrict__ Wfc, const float* __restrict__ bfc,
    float* __restrict__ out, int ntiles) {
    int tile = blockIdx.x * 4 + (threadIdx.x >> 6);
    if (tile >= ntiles) return;
    int lane = threadIdx.x & 63;
    int sub = lane & 15;
    int quad = lane >> 4;
    int row = tile * 16 + sub;

    floatx4 acc0 = {0.f, 0.f, 0.f, 0.f};
    floatx4 acc1 = {0.f, 0.f, 0.f, 0.f};
    floatx4 acc2 = {0.f, 0.f, 0.f, 0.f};
    floatx4 acc3 = {0.f, 0.f, 0.f, 0.f};

    const _Float16* zrow = (const _Float16*)zm2 + (size_t)row * 64 + quad * 8;
    const _Float16* hrow = (const _Float16*)h1 + (size_t)row * 64 + quad * 8;
    const _Float16* wb = (const _Float16*)wbuf2 + (size_t)lane * 8;

    half8 amat[4];
    amat[0] = *(const half8*)(zrow);
    amat[1] = *(const half8*)(zrow + 32);
    amat[2] = *(const half8*)(hrow);
    amat[3] = *(const half8*)(hrow + 32);

#pragma unroll
    for (int ks = 0; ks < 4; ++ks) {
        half8 a = amat[ks];
        half8 b0 = *(const half8*)(wb + (size_t)(ks * 4 + 0) * 512);
        half8 b1 = *(const half8*)(wb + (size_t)(ks * 4 + 1) * 512);
        half8 b2 = *(const half8*)(wb + (size_t)(ks * 4 + 2) * 512);
        half8 b3 = *(const half8*)(wb + (size_t)(ks * 4 + 3) * 512);
        acc0 = __builtin_amdgcn_mfma_f32_16x16x32_f16(a, b0, acc0, 0, 0, 0);
        acc1 = __builtin_amdgcn_mfma_f32_16x16x32_f16(a, b1, acc1, 0, 0, 0);
        acc2 = __builtin_amdgcn_mfma_f32_16x16x32_f16(a, b2, acc2, 0, 0, 0);
        acc3 = __builtin_amdgcn_mfma_f32_16x16x32_f16(a, b3, acc3, 0, 0, 0);
    }
    float bb0 = b2l[sub], bb1 = b2l[16 + sub], bb2 = b2l[32 + sub], bb3 = b2l[48 + sub];
    float wv0 = Wfc[sub], wv1 = Wfc[16 + sub], wv2 = Wfc[32 + sub], wv3 = Wfc[48 + sub];
    float p[4];
#pragma unroll
    for (int reg = 0; reg < 4; ++reg) {
        p[reg] = fmaxf(acc0[reg] + bb0, 0.f) * wv0
               + fmaxf(acc1[reg] + bb1, 0.f) * wv1
               + fmaxf(acc2[reg] + bb2, 0.f) * wv2
               + fmaxf(acc3[reg] + bb3, 0.f) * wv3;
    }
#pragma unroll
    for (int m = 1; m <= 8; m <<= 1) {
#pragma unroll
        for (int reg = 0; reg < 4; ++reg) p[reg] += __shfl_xor(p[reg], m, 64);
    }
    if (sub == 0) {
        float b0 = bfc[0];
#pragma unroll
        for (int reg = 0; reg < 4; ++reg)
            out[tile * 16 + quad * 4 + reg] = p[reg] + b0;
    }
}

extern "C" void kernel_launch(void* const* d_in, const int* in_sizes, int n_in,
                              void* d_out, int out_size, void* d_ws, size_t ws_size,
                              hipStream_t stream) {
    const float* x   = (const float*)d_in[0];
    const int*   ei  = (const int*)d_in[1];
    const float* tau = (const float*)d_in[2];
    const float* W1l = (const float*)d_in[3];
    const float* b1l = (const float*)d_in[4];
    const float* W1r = (const float*)d_in[5];
    const float* W2l = (const float*)d_in[6];
    const float* b2l = (const float*)d_in[7];
    const float* W2r = (const float*)d_in[8];
    const float* Wfc = (const float*)d_in[9];
    const float* bfc = (const float*)d_in[10];
    float* out = (float*)d_out;

    const int N = in_sizes[0] / 64;   // 100000
    const int E = in_sizes[1] / 2;    // 3200000 (== NBLK * PER)
    const int* src = ei;
    const int* dst = ei + E;

    char* w = (char*)d_ws;
    auto take = [&](size_t b) { char* p = w; w += (b + 255) & ~(size_t)255; return p; };
    int*           histT  = (int*)take((size_t)NBKT * NBLK * 4);  // 1.6 MB
    int*           btot   = (int*)take((size_t)NBKT * 4);
    int*           bstart = (int*)take((size_t)(NBKT + 1) * 4);
    int*           binned = (int*)take((size_t)(E + 64) * 4);     // 12.8 MB (+pad)
    int*           nodeoff= (int*)take((size_t)(N + 2) * 4);      // 400 KB
    __half*        xh     = (__half*)take((size_t)N * 64 * 2);    // 12.8 MB
    unsigned char* xf8a   = (unsigned char*)take((size_t)N * 32); // 3.2 MB
    unsigned char* xf8b   = (unsigned char*)take((size_t)N * 32); // 3.2 MB
    __half*        h1     = (__half*)take((size_t)N * 64 * 2);    // 12.8 MB
    unsigned char* h1f8a  = (unsigned char*)take((size_t)N * 32); // 3.2 MB
    unsigned char* h1f8b  = (unsigned char*)take((size_t)N * 32); // 3.2 MB
    __half*        zm1    = (__half*)take((size_t)N * 64 * 2);    // 12.8 MB
    __half*        mt1    = (__half*)take((size_t)N * 2);
    __half*        zm2    = (__half*)take((size_t)N * 64 * 2);    // 12.8 MB
    __half*        wbuf1  = (__half*)take(1280 * 8 * 2);          // 20 KB
    __half*        wbuf2  = (__half*)take(1024 * 8 * 2);          // 16 KB

    int n4 = N * 16;                       // float4 elements of x
    int hpblocks = NBLK + 9 + (n4 + 255) / 256;
    int ntiles = N / 16;                   // 6250 (exact)
    int gblocks = (ntiles + 3) / 4;        // 1563
    int ablocks = (N + 63) / 64;           // 1563 aggr blocks (64 nodes each)

    k_histprep<<<hpblocks, 256, 0, stream>>>(dst, histT, E, x, xh, xf8a, xf8b, n4,
                                             W1l, W1r, W2l, W2r, wbuf1, wbuf2);
    k_scanblk <<<NBKT, NBLK, 0, stream>>>(histT, btot);
    k_scanbkt <<<1, 1024, 0, stream>>>(btot, bstart);
    k_scatter <<<NBLK, 256, 0, stream>>>(src, dst, histT, bstart, binned, E);
    k_csr     <<<NBKT, 512, 0, stream>>>(binned, bstart, nodeoff, E, N);
    k_aggrh<true>  <<<ablocks, AB2, 0, stream>>>(binned, nodeoff, xf8a, tau, zm1, 0, mt1, N);
    k_aggrh<false> <<<ablocks, AB2, 0, stream>>>(binned, nodeoff, xf8b, tau, zm1, 32, mt1, N);
    k_gemm1   <<<gblocks, 256, 0, stream>>>(zm1, mt1, xh, tau, wbuf1, b1l, h1, h1f8a, h1f8b, ntiles);
    k_aggrh<false> <<<ablocks, AB2, 0, stream>>>(binned, nodeoff, h1f8a, tau, zm2, 0, mt1, N);
    k_aggrh<false> <<<ablocks, AB2, 0, stream>>>(binned, nodeoff, h1f8b, tau, zm2, 32, mt1, N);
    k_gemm2   <<<gblocks, 256, 0, stream>>>(zm2, h1, wbuf2, b2l, Wfc, bfc, out, ntiles);
}

// Round 8
// 259.611 us; speedup vs baseline: 1.1821x; 1.1821x over previous
//
#include <hip/hip_runtime.h>
#include <hip/hip_bf16.h>
#include <hip/hip_fp16.h>
#include <hip/hip_fp8.h>

// GQNN: 2-layer GraphSAGE (mean aggr) + fc head. N=100k, E=3.2M, d=64/65.
// R24: occupancy via small blocks. R23 post-mortem: L2-residence confirmed
// (FETCH 112->33MB/pass) but time ~flat => gather cost tracks DISTINCT
// SEGMENTS, not bytes/latency/instructions; R23's 32B split doubled segments
// per row -> worse. Revert to R22 64B-row structure (1 line/edge, best
// segments/byte). New lever: 2-wave 128-thr blocks (8 nodes each, grid 12500,
// __launch_bounds__(128,8)) — occupancy never exceeded 52% with 4-wave
// blocks; small blocks pack to 16 blocks/CU = 100% waves. If dur doesn't
// move at high occupancy, request-throughput roofline is established.
// CSR (R21), scatter, scans, gemms unchanged from R22.

#define BSH 7                    // bucket shift: 128 nodes per bucket
#define NBKT 782                 // ceil(100000 / 128)
#define NBLK 512                 // binning blocks
#define PER 6250                 // edges per scatter block (E/NBLK)
#define CAP 6144                 // bucket edge capacity (mean 4096, sigma 64)
#define AB2 128                  // aggr block threads (2 waves)

typedef _Float16 half8 __attribute__((ext_vector_type(8)));
typedef float floatx4 __attribute__((ext_vector_type(4)));
typedef float floatx2 __attribute__((ext_vector_type(2)));
typedef int intx4 __attribute__((ext_vector_type(4)));

struct h4s { __half2 lo, hi; };  // 8B fp16 row chunk

// ---- fp8 (OCP e4m3) decode/encode via hw instructions ----
#if __has_builtin(__builtin_amdgcn_cvt_pk_f32_fp8)
template <bool HI>
__device__ __forceinline__ float2 f8x2_to_f2(int v) {
    floatx2 r = __builtin_amdgcn_cvt_pk_f32_fp8(v, HI);
    return make_float2(r.x, r.y);
}
#else
template <bool HI>
__device__ __forceinline__ float2 f8x2_to_f2(int v) {
    unsigned short u = HI ? (unsigned short)(((unsigned)v) >> 16)
                          : (unsigned short)(v & 0xFFFF);
    __half2_raw r = __hip_cvt_fp8x2_to_halfraw2((__hip_fp8x2_storage_t)u, __HIP_E4M3);
    return __half22float2(*(__half2*)&r);
}
#endif

#if __has_builtin(__builtin_amdgcn_cvt_pk_fp8_f32)
__device__ __forceinline__ unsigned f4_to_f8x4(float a, float b, float c, float d) {
    int lo = __builtin_amdgcn_cvt_pk_fp8_f32(a, b, 0, false);
    return (unsigned)__builtin_amdgcn_cvt_pk_fp8_f32(c, d, lo, true);
}
__device__ __forceinline__ unsigned char f_to_f8(float a) {
    return (unsigned char)(__builtin_amdgcn_cvt_pk_fp8_f32(a, a, 0, false) & 0xFF);
}
#else
__device__ __forceinline__ unsigned f4_to_f8x4(float a, float b, float c, float d) {
    unsigned lo = (unsigned)__hip_cvt_float2_to_fp8x2(make_float2(a, b), __HIP_SATFINITE, __HIP_E4M3);
    unsigned hi = (unsigned)__hip_cvt_float2_to_fp8x2(make_float2(c, d), __HIP_SATFINITE, __HIP_E4M3);
    return lo | (hi << 16);
}
__device__ __forceinline__ unsigned char f_to_f8(float a) {
    return (unsigned char)__hip_cvt_float_to_fp8(a, __HIP_SATFINITE, __HIP_E4M3);
}
#endif

// ---------------- hist + prep (fused; k-major histT) ----------------
__global__ __launch_bounds__(256) void k_histprep(
    const int* __restrict__ dst, int* __restrict__ histT, int E,
    const float* __restrict__ x, __half* __restrict__ xh,
    unsigned char* __restrict__ xf8, int n4,
    const float* __restrict__ W1l, const float* __restrict__ W1r,
    const float* __restrict__ W2l, const float* __restrict__ W2r,
    __half* __restrict__ wbuf1, __half* __restrict__ wbuf2) {
    if (blockIdx.x < NBLK) {
        __shared__ int h[NBKT];
        for (int i = threadIdx.x; i < NBKT; i += 256) h[i] = 0;
        __syncthreads();
        int lo = blockIdx.x * PER;
        int hi = lo + PER; if (hi > E) hi = E;
        for (int e = lo + threadIdx.x; e < hi; e += 256)
            atomicAdd(&h[dst[e] >> BSH], 1);
        __syncthreads();
        for (int k = threadIdx.x; k < NBKT; k += 256)
            histT[k * NBLK + blockIdx.x] = h[k];
    } else if (blockIdx.x < NBLK + 9) {
        int idx = (blockIdx.x - NBLK) * 256 + threadIdx.x;
        if (idx < 1280) {
            int lane = idx & 63;
            int nt = (idx >> 6) & 3;
            int kstep = idx >> 8;
            int col = nt * 16 + (lane & 15);
            int kbase = kstep * 32 + (lane >> 4) * 8;
#pragma unroll
            for (int j = 0; j < 8; ++j) {
                int k = kbase + j;
                float v;
                if (k < 64)        v = W1l[k * 64 + col];
                else if (k < 128)  v = W1r[(k - 64) * 64 + col];
                else if (k == 128) v = W1l[64 * 64 + col];
                else if (k == 129) v = W1r[64 * 64 + col];
                else v = 0.f;
                wbuf1[(size_t)idx * 8 + j] = __float2half(v);
            }
        } else if (idx < 1280 + 1024) {
            int i2 = idx - 1280;
            int lane = i2 & 63;
            int nt = (i2 >> 6) & 3;
            int kstep = i2 >> 8;
            int col = nt * 16 + (lane & 15);
            int kbase = kstep * 32 + (lane >> 4) * 8;
#pragma unroll
            for (int j = 0; j < 8; ++j) {
                int k = kbase + j;
                float v = (k < 64) ? W2l[k * 64 + col] : W2r[(k - 64) * 64 + col];
                wbuf2[(size_t)i2 * 8 + j] = __float2half(v);
            }
        }
    } else {
        int i = (blockIdx.x - NBLK - 9) * 256 + threadIdx.x;
        if (i < n4) {
            float4 v = ((const float4*)x)[i];
            ((__half2*)xh)[2 * i]     = __floats2half2_rn(v.x, v.y);
            ((__half2*)xh)[2 * i + 1] = __floats2half2_rn(v.z, v.w);
            ((unsigned*)xf8)[i] = f4_to_f8x4(v.x, v.y, v.z, v.w);
        }
    }
}

// ---------------- scans ----------------

__global__ __launch_bounds__(NBLK) void k_scanblk(int* __restrict__ histT,
                                                  int* __restrict__ btot) {
    __shared__ int s[NBLK];
    int k = blockIdx.x, t = threadIdx.x;
    int v = histT[k * NBLK + t];
    s[t] = v;
    __syncthreads();
    for (int off = 1; off < NBLK; off <<= 1) {
        int u = (t >= off) ? s[t - off] : 0;
        __syncthreads();
        s[t] += u;
        __syncthreads();
    }
    histT[k * NBLK + t] = s[t] - v;
    if (t == NBLK - 1) btot[k] = s[t];
}

__global__ __launch_bounds__(1024) void k_scanbkt(const int* __restrict__ btot,
                                                  int* __restrict__ bstart) {
    __shared__ int s[1024];
    int t = threadIdx.x;
    int v = (t < NBKT) ? btot[t] : 0;
    s[t] = v;
    __syncthreads();
    for (int off = 1; off < 1024; off <<= 1) {
        int u = (t >= off) ? s[t - off] : 0;
        __syncthreads();
        s[t] += u;
        __syncthreads();
    }
    if (t < NBKT) bstart[t] = s[t] - v;
    if (t == NBKT - 1) bstart[NBKT] = s[t];
}

// ---------------- scatter: LDS counting sort + quarter-wave burst writes ------
__global__ __launch_bounds__(256) void k_scatter(const int* __restrict__ src,
                                                 const int* __restrict__ dst,
                                                 const int* __restrict__ histT,
                                                 const int* __restrict__ bstart,
                                                 int* __restrict__ binned, int E) {
    __shared__ int sorted[PER];          // 25 KB
    __shared__ int lstart[NBKT + 1];
    __shared__ int cur[NBKT];
    __shared__ int gst[NBKT];
    __shared__ int tsum[256];
    int b = blockIdx.x, t = threadIdx.x;
    int base = b * PER;
    int blen = E - base; if (blen > PER) blen = PER;

    for (int k = t; k < NBKT; k += 256) lstart[k] = 0;
    __syncthreads();
    for (int e = base + t; e < base + blen; e += 256)
        atomicAdd(&lstart[dst[e] >> BSH], 1);
    __syncthreads();
    int c0 = 0;
    int i0 = t * 4;
#pragma unroll
    for (int j = 0; j < 4; ++j)
        if (i0 + j < NBKT) c0 += lstart[i0 + j];
    tsum[t] = c0;
    __syncthreads();
    for (int off = 1; off < 256; off <<= 1) {
        int u = (t >= off) ? tsum[t - off] : 0;
        __syncthreads();
        tsum[t] += u;
        __syncthreads();
    }
    int running = tsum[t] - c0;
    __syncthreads();
#pragma unroll
    for (int j = 0; j < 4; ++j) {
        int i = i0 + j;
        if (i < NBKT) {
            int v = lstart[i];
            lstart[i] = running;
            running += v;
        }
    }
    __syncthreads();
    if (t == 0) lstart[NBKT] = blen;
    for (int k = t; k < NBKT; k += 256) {
        cur[k] = lstart[k];
        gst[k] = bstart[k] + histT[k * NBLK + b];
    }
    __syncthreads();
    for (int e = base + t; e < base + blen; e += 256) {
        int d = dst[e], s = src[e];
        int pos = atomicAdd(&cur[d >> BSH], 1);
        sorted[pos] = (s << BSH) | (d & ((1 << BSH) - 1));
    }
    __syncthreads();
    int qw = t >> 4, ql = t & 15;
    for (int k = qw; k < NBKT; k += 16) {
        int st = lstart[k];
        int ln = lstart[k + 1] - st;
        int gd = gst[k];
        for (int i = ql; i < ln; i += 16)
            binned[gd + i] = sorted[st + i];
    }
}

// ---------------- CSR finalize: sort each bucket by node, in-place ----------
__global__ __launch_bounds__(512) void k_csr(int* __restrict__ binned,
                                             const int* __restrict__ bstart,
                                             int* __restrict__ nodeoff,
                                             int E, int N) {
    __shared__ int cnt[128], sarr[128], cur[128];
    __shared__ int sorted[CAP];          // 24 KB
    int k = blockIdx.x, t = threadIdx.x;
    int lo = bstart[k], hi = bstart[k + 1];
    if (t < 128) cnt[t] = 0;
    __syncthreads();
    for (int eb = lo; eb < hi; eb += 512 * 4) {
        int e0 = eb + t, e1 = e0 + 512, e2 = e0 + 1024, e3 = e0 + 1536;
        int p0 = (e0 < hi) ? binned[e0] : -1;
        int p1 = (e1 < hi) ? binned[e1] : -1;
        int p2 = (e2 < hi) ? binned[e2] : -1;
        int p3 = (e3 < hi) ? binned[e3] : -1;
        if (p0 >= 0) atomicAdd(&cnt[p0 & 127], 1);
        if (p1 >= 0) atomicAdd(&cnt[p1 & 127], 1);
        if (p2 >= 0) atomicAdd(&cnt[p2 & 127], 1);
        if (p3 >= 0) atomicAdd(&cnt[p3 & 127], 1);
    }
    __syncthreads();
    if (t < 128) sarr[t] = cnt[t];
    __syncthreads();
    for (int off = 1; off < 128; off <<= 1) {
        int u = 0;
        if (t < 128 && t >= off) u = sarr[t - off];
        __syncthreads();
        if (t < 128) sarr[t] += u;
        __syncthreads();
    }
    if (t < 128) {
        int excl = sarr[t] - cnt[t];
        cur[t] = excl;
        int node = (k << BSH) + t;
        if (node < N) nodeoff[node] = lo + excl;
    }
    if (k == NBKT - 1 && t == 0) nodeoff[N] = E;
    __syncthreads();
    for (int eb = lo; eb < hi; eb += 512 * 4) {
        int e0 = eb + t, e1 = e0 + 512, e2 = e0 + 1024, e3 = e0 + 1536;
        int p0 = (e0 < hi) ? binned[e0] : -1;
        int p1 = (e1 < hi) ? binned[e1] : -1;
        int p2 = (e2 < hi) ? binned[e2] : -1;
        int p3 = (e3 < hi) ? binned[e3] : -1;
        if (p0 >= 0) { int pos = atomicAdd(&cur[p0 & 127], 1); if (pos < CAP) sorted[pos] = p0 >> BSH; }
        if (p1 >= 0) { int pos = atomicAdd(&cur[p1 & 127], 1); if (pos < CAP) sorted[pos] = p1 >> BSH; }
        if (p2 >= 0) { int pos = atomicAdd(&cur[p2 & 127], 1); if (pos < CAP) sorted[pos] = p2 >> BSH; }
        if (p3 >= 0) { int pos = atomicAdd(&cur[p3 & 127], 1); if (pos < CAP) sorted[pos] = p3 >> BSH; }
    }
    __syncthreads();
    int len = hi - lo; if (len > CAP) len = CAP;
    for (int i = t; i < len; i += 512)
        binned[lo + i] = sorted[i];
}

// ---------------- aggregation (no LDS; 2-wave blocks, 8 nodes each) --------
// Quarter q owns one node; lane (ch=c>>2, g=c&3) loads 16B chunk ch of
// neighbor slot 4j+g via dwordx4 (16 rows/instr). Straight-line rounds,
// intx4 AND-mask, scalar-select sanitize, depth-2 index prefetch (R22).

// zm1[node][64] = mean_x (fp16); mt1[node] = mean_tau (fp16)
__global__ __launch_bounds__(AB2, 8) void k_aggrb1(
    const int* __restrict__ nbr, const int* __restrict__ nodeoff,
    const unsigned char* __restrict__ xf8, const float* __restrict__ tau,
    __half* __restrict__ zm1, __half* __restrict__ mt1, int N) {
    int t = threadIdx.x;
    int lane = t & 63;
    int q = lane >> 4;
    int c = lane & 15;
    int g = c & 3;                      // neighbor-slot within a group of 4
    int ch = c >> 2;                    // 16B chunk index within the 64B row
    unsigned cb = (unsigned)(ch << 4);  // chunk byte offset
    const char* xb = (const char*)xf8;
    int nb = blockIdx.x << 3;           // 8 nodes per block (2 waves x 4)

    {
        int p = t >> 6;                 // wave id 0/1
        int ld = (p << 2) + q;
        int node = nb + ld;
        int off0 = 0, off1 = 0;
        if (node < N) { off0 = nodeoff[node]; off1 = nodeoff[node + 1]; }
        int d = off1 - off0;
        int dm = d;
        dm = max(dm, __shfl_xor(dm, 16, 64));
        dm = max(dm, __shfl_xor(dm, 32, 64));
        float4 A0 = {0.f, 0.f, 0.f, 0.f}, A1 = A0, A2 = A0, A3 = A0;
        float sumtau = 0.f;
        // prefetch round-0 index words (binned padded: overrun reads safe)
        int base0 = off0 + g;
        int nx0 = nbr[base0];
        int nx1 = nbr[base0 + 4];
        int nx2 = nbr[base0 + 8];
        int nx3 = nbr[base0 + 12];
        for (int base = 0; base < dm; base += 16) {
            int s0 = base + g;
            bool v0 = s0 < d, v1 = s0 + 4 < d, v2 = s0 + 8 < d, v3 = s0 + 12 < d;
            int cu0 = nx0, cu1 = nx1, cu2 = nx2, cu3 = nx3;
            // prefetch next round's index words (pipeline depth 2)
            int bn = base0 + base + 16;
            nx0 = nbr[bn];
            nx1 = nbr[bn + 4];
            nx2 = nbr[bn + 8];
            nx3 = nbr[bn + 12];
            int sx0 = v0 ? cu0 : 0;     // sanitize gather row
            int sx1 = v1 ? cu1 : 0;
            int sx2 = v2 ? cu2 : 0;
            int sx3 = v3 ? cu3 : 0;
            intx4 r0 = *(const intx4*)(xb + (((unsigned)sx0 << 6) + cb));
            intx4 r1 = *(const intx4*)(xb + (((unsigned)sx1 << 6) + cb));
            intx4 r2 = *(const intx4*)(xb + (((unsigned)sx2 << 6) + cb));
            intx4 r3 = *(const intx4*)(xb + (((unsigned)sx3 << 6) + cb));
            float ta0 = tau[sx0], ta1 = tau[sx1], ta2 = tau[sx2], ta3 = tau[sx3];
            sumtau += (v0 ? ta0 : 0.f) + (v1 ? ta1 : 0.f)
                    + (v2 ? ta2 : 0.f) + (v3 ? ta3 : 0.f);
            int m0 = v0 ? -1 : 0, m1 = v1 ? -1 : 0, m2 = v2 ? -1 : 0, m3 = v3 ? -1 : 0;
            r0 &= (intx4){m0, m0, m0, m0};
            r1 &= (intx4){m1, m1, m1, m1};
            r2 &= (intx4){m2, m2, m2, m2};
            r3 &= (intx4){m3, m3, m3, m3};
            {
                float2 l0 = f8x2_to_f2<false>(r0.x), h0 = f8x2_to_f2<true>(r0.x);
                float2 l1 = f8x2_to_f2<false>(r0.y), h1v = f8x2_to_f2<true>(r0.y);
                float2 l2 = f8x2_to_f2<false>(r0.z), h2v = f8x2_to_f2<true>(r0.z);
                float2 l3 = f8x2_to_f2<false>(r0.w), h3v = f8x2_to_f2<true>(r0.w);
                A0.x += l0.x; A0.y += l0.y; A0.z += h0.x; A0.w += h0.y;
                A1.x += l1.x; A1.y += l1.y; A1.z += h1v.x; A1.w += h1v.y;
                A2.x += l2.x; A2.y += l2.y; A2.z += h2v.x; A2.w += h2v.y;
                A3.x += l3.x; A3.y += l3.y; A3.z += h3v.x; A3.w += h3v.y;
            }
            {
                float2 l0 = f8x2_to_f2<false>(r1.x), h0 = f8x2_to_f2<true>(r1.x);
                float2 l1 = f8x2_to_f2<false>(r1.y), h1v = f8x2_to_f2<true>(r1.y);
                float2 l2 = f8x2_to_f2<false>(r1.z), h2v = f8x2_to_f2<true>(r1.z);
                float2 l3 = f8x2_to_f2<false>(r1.w), h3v = f8x2_to_f2<true>(r1.w);
                A0.x += l0.x; A0.y += l0.y; A0.z += h0.x; A0.w += h0.y;
                A1.x += l1.x; A1.y += l1.y; A1.z += h1v.x; A1.w += h1v.y;
                A2.x += l2.x; A2.y += l2.y; A2.z += h2v.x; A2.w += h2v.y;
                A3.x += l3.x; A3.y += l3.y; A3.z += h3v.x; A3.w += h3v.y;
            }
            {
                float2 l0 = f8x2_to_f2<false>(r2.x), h0 = f8x2_to_f2<true>(r2.x);
                float2 l1 = f8x2_to_f2<false>(r2.y), h1v = f8x2_to_f2<true>(r2.y);
                float2 l2 = f8x2_to_f2<false>(r2.z), h2v = f8x2_to_f2<true>(r2.z);
                float2 l3 = f8x2_to_f2<false>(r2.w), h3v = f8x2_to_f2<true>(r2.w);
                A0.x += l0.x; A0.y += l0.y; A0.z += h0.x; A0.w += h0.y;
                A1.x += l1.x; A1.y += l1.y; A1.z += h1v.x; A1.w += h1v.y;
                A2.x += l2.x; A2.y += l2.y; A2.z += h2v.x; A2.w += h2v.y;
                A3.x += l3.x; A3.y += l3.y; A3.z += h3v.x; A3.w += h3v.y;
            }
            {
                float2 l0 = f8x2_to_f2<false>(r3.x), h0 = f8x2_to_f2<true>(r3.x);
                float2 l1 = f8x2_to_f2<false>(r3.y), h1v = f8x2_to_f2<true>(r3.y);
                float2 l2 = f8x2_to_f2<false>(r3.z), h2v = f8x2_to_f2<true>(r3.z);
                float2 l3 = f8x2_to_f2<false>(r3.w), h3v = f8x2_to_f2<true>(r3.w);
                A0.x += l0.x; A0.y += l0.y; A0.z += h0.x; A0.w += h0.y;
                A1.x += l1.x; A1.y += l1.y; A1.z += h1v.x; A1.w += h1v.y;
                A2.x += l2.x; A2.y += l2.y; A2.z += h2v.x; A2.w += h2v.y;
                A3.x += l3.x; A3.y += l3.y; A3.z += h3v.x; A3.w += h3v.y;
            }
        }
        // combine the 4 neighbor-groups: butterfly over g (lanes c^1, c^2);
        // every lane ends with the full sum, so all 16 lanes write below.
#pragma unroll
        for (int off = 1; off <= 2; off <<= 1) {
            A0.x += __shfl_xor(A0.x, off, 64); A0.y += __shfl_xor(A0.y, off, 64);
            A0.z += __shfl_xor(A0.z, off, 64); A0.w += __shfl_xor(A0.w, off, 64);
            A1.x += __shfl_xor(A1.x, off, 64); A1.y += __shfl_xor(A1.y, off, 64);
            A1.z += __shfl_xor(A1.z, off, 64); A1.w += __shfl_xor(A1.w, off, 64);
            A2.x += __shfl_xor(A2.x, off, 64); A2.y += __shfl_xor(A2.y, off, 64);
            A2.z += __shfl_xor(A2.z, off, 64); A2.w += __shfl_xor(A2.w, off, 64);
            A3.x += __shfl_xor(A3.x, off, 64); A3.y += __shfl_xor(A3.y, off, 64);
            A3.z += __shfl_xor(A3.z, off, 64); A3.w += __shfl_xor(A3.w, off, 64);
            sumtau += __shfl_xor(sumtau, off, 64);
        }
        float inv = 1.f / fmaxf((float)d, 1.f);
        if (node < N) {
            // lane (ch,g) writes dword g of chunk ch = cols ch*16 + g*4 .. +4
            float4 Aw = (g == 0) ? A0 : ((g == 1) ? A1 : ((g == 2) ? A2 : A3));
            h4s o;
            o.lo = __floats2half2_rn(Aw.x * inv, Aw.y * inv);
            o.hi = __floats2half2_rn(Aw.z * inv, Aw.w * inv);
            *(h4s*)(zm1 + (size_t)node * 64 + (ch << 4) + (g << 2)) = o;
            if (c == 0) mt1[node] = __float2half(sumtau * inv);
        }
    }
}

// zm2[node][64] = mean_h1 (fp16), gathered from h1f8
__global__ __launch_bounds__(AB2, 8) void k_aggrb2(
    const int* __restrict__ nbr, const int* __restrict__ nodeoff,
    const unsigned char* __restrict__ h1f8, __half* __restrict__ zm2, int N) {
    int t = threadIdx.x;
    int lane = t & 63;
    int q = lane >> 4;
    int c = lane & 15;
    int g = c & 3;
    int ch = c >> 2;
    unsigned cb = (unsigned)(ch << 4);
    const char* hb = (const char*)h1f8;
    int nb = blockIdx.x << 3;

    {
        int p = t >> 6;
        int ld = (p << 2) + q;
        int node = nb + ld;
        int off0 = 0, off1 = 0;
        if (node < N) { off0 = nodeoff[node]; off1 = nodeoff[node + 1]; }
        int d = off1 - off0;
        int dm = d;
        dm = max(dm, __shfl_xor(dm, 16, 64));
        dm = max(dm, __shfl_xor(dm, 32, 64));
        float4 A0 = {0.f, 0.f, 0.f, 0.f}, A1 = A0, A2 = A0, A3 = A0;
        int base0 = off0 + g;
        int nx0 = nbr[base0];
        int nx1 = nbr[base0 + 4];
        int nx2 = nbr[base0 + 8];
        int nx3 = nbr[base0 + 12];
        for (int base = 0; base < dm; base += 16) {
            int s0 = base + g;
            bool v0 = s0 < d, v1 = s0 + 4 < d, v2 = s0 + 8 < d, v3 = s0 + 12 < d;
            int cu0 = nx0, cu1 = nx1, cu2 = nx2, cu3 = nx3;
            int bn = base0 + base + 16;
            nx0 = nbr[bn];
            nx1 = nbr[bn + 4];
            nx2 = nbr[bn + 8];
            nx3 = nbr[bn + 12];
            int sx0 = v0 ? cu0 : 0;
            int sx1 = v1 ? cu1 : 0;
            int sx2 = v2 ? cu2 : 0;
            int sx3 = v3 ? cu3 : 0;
            intx4 r0 = *(const intx4*)(hb + (((unsigned)sx0 << 6) + cb));
            intx4 r1 = *(const intx4*)(hb + (((unsigned)sx1 << 6) + cb));
            intx4 r2 = *(const intx4*)(hb + (((unsigned)sx2 << 6) + cb));
            intx4 r3 = *(const intx4*)(hb + (((unsigned)sx3 << 6) + cb));
            int m0 = v0 ? -1 : 0, m1 = v1 ? -1 : 0, m2 = v2 ? -1 : 0, m3 = v3 ? -1 : 0;
            r0 &= (intx4){m0, m0, m0, m0};
            r1 &= (intx4){m1, m1, m1, m1};
            r2 &= (intx4){m2, m2, m2, m2};
            r3 &= (intx4){m3, m3, m3, m3};
            {
                float2 l0 = f8x2_to_f2<false>(r0.x), h0 = f8x2_to_f2<true>(r0.x);
                float2 l1 = f8x2_to_f2<false>(r0.y), h1v = f8x2_to_f2<true>(r0.y);
                float2 l2 = f8x2_to_f2<false>(r0.z), h2v = f8x2_to_f2<true>(r0.z);
                float2 l3 = f8x2_to_f2<false>(r0.w), h3v = f8x2_to_f2<true>(r0.w);
                A0.x += l0.x; A0.y += l0.y; A0.z += h0.x; A0.w += h0.y;
                A1.x += l1.x; A1.y += l1.y; A1.z += h1v.x; A1.w += h1v.y;
                A2.x += l2.x; A2.y += l2.y; A2.z += h2v.x; A2.w += h2v.y;
                A3.x += l3.x; A3.y += l3.y; A3.z += h3v.x; A3.w += h3v.y;
            }
            {
                float2 l0 = f8x2_to_f2<false>(r1.x), h0 = f8x2_to_f2<true>(r1.x);
                float2 l1 = f8x2_to_f2<false>(r1.y), h1v = f8x2_to_f2<true>(r1.y);
                float2 l2 = f8x2_to_f2<false>(r1.z), h2v = f8x2_to_f2<true>(r1.z);
                float2 l3 = f8x2_to_f2<false>(r1.w), h3v = f8x2_to_f2<true>(r1.w);
                A0.x += l0.x; A0.y += l0.y; A0.z += h0.x; A0.w += h0.y;
                A1.x += l1.x; A1.y += l1.y; A1.z += h1v.x; A1.w += h1v.y;
                A2.x += l2.x; A2.y += l2.y; A2.z += h2v.x; A2.w += h2v.y;
                A3.x += l3.x; A3.y += l3.y; A3.z += h3v.x; A3.w += h3v.y;
            }
            {
                float2 l0 = f8x2_to_f2<false>(r2.x), h0 = f8x2_to_f2<true>(r2.x);
                float2 l1 = f8x2_to_f2<false>(r2.y), h1v = f8x2_to_f2<true>(r2.y);
                float2 l2 = f8x2_to_f2<false>(r2.z), h2v = f8x2_to_f2<true>(r2.z);
                float2 l3 = f8x2_to_f2<false>(r2.w), h3v = f8x2_to_f2<true>(r2.w);
                A0.x += l0.x; A0.y += l0.y; A0.z += h0.x; A0.w += h0.y;
                A1.x += l1.x; A1.y += l1.y; A1.z += h1v.x; A1.w += h1v.y;
                A2.x += l2.x; A2.y += l2.y; A2.z += h2v.x; A2.w += h2v.y;
                A3.x += l3.x; A3.y += l3.y; A3.z += h3v.x; A3.w += h3v.y;
            }
            {
                float2 l0 = f8x2_to_f2<false>(r3.x), h0 = f8x2_to_f2<true>(r3.x);
                float2 l1 = f8x2_to_f2<false>(r3.y), h1v = f8x2_to_f2<true>(r3.y);
                float2 l2 = f8x2_to_f2<false>(r3.z), h2v = f8x2_to_f2<true>(r3.z);
                float2 l3 = f8x2_to_f2<false>(r3.w), h3v = f8x2_to_f2<true>(r3.w);
                A0.x += l0.x; A0.y += l0.y; A0.z += h0.x; A0.w += h0.y;
                A1.x += l1.x; A1.y += l1.y; A1.z += h1v.x; A1.w += h1v.y;
                A2.x += l2.x; A2.y += l2.y; A2.z += h2v.x; A2.w += h2v.y;
                A3.x += l3.x; A3.y += l3.y; A3.z += h3v.x; A3.w += h3v.y;
            }
        }
#pragma unroll
        for (int off = 1; off <= 2; off <<= 1) {
            A0.x += __shfl_xor(A0.x, off, 64); A0.y += __shfl_xor(A0.y, off, 64);
            A0.z += __shfl_xor(A0.z, off, 64); A0.w += __shfl_xor(A0.w, off, 64);
            A1.x += __shfl_xor(A1.x, off, 64); A1.y += __shfl_xor(A1.y, off, 64);
            A1.z += __shfl_xor(A1.z, off, 64); A1.w += __shfl_xor(A1.w, off, 64);
            A2.x += __shfl_xor(A2.x, off, 64); A2.y += __shfl_xor(A2.y, off, 64);
            A2.z += __shfl_xor(A2.z, off, 64); A2.w += __shfl_xor(A2.w, off, 64);
            A3.x += __shfl_xor(A3.x, off, 64); A3.y += __shfl_xor(A3.y, off, 64);
            A3.z += __shfl_xor(A3.z, off, 64); A3.w += __shfl_xor(A3.w, off, 64);
        }
        float inv = 1.f / fmaxf((float)d, 1.f);
        if (node < N) {
            float4 Aw = (g == 0) ? A0 : ((g == 1) ? A1 : ((g == 2) ? A2 : A3));
            h4s o;
            o.lo = __floats2half2_rn(Aw.x * inv, Aw.y * inv);
            o.hi = __floats2half2_rn(Aw.z * inv, Aw.w * inv);
            *(h4s*)(zm2 + (size_t)node * 64 + (ch << 4) + (g << 2)) = o;
        }
    }
}

// ---------------- MFMA GEMM kernels (unchanged from R13) ----------------

__global__ __launch_bounds__(256) void k_gemm1(
    const __half* __restrict__ zm1, const __half* __restrict__ mt1,
    const __half* __restrict__ xh, const float* __restrict__ tau,
    const __half* __restrict__ wbuf1, const float* __restrict__ b1l,
    __half* __restrict__ h1, unsigned char* __restrict__ h1f8, int ntiles) {
    int tile = blockIdx.x * 4 + (threadIdx.x >> 6);
    if (tile >= ntiles) return;
    int lane = threadIdx.x & 63;
    int sub = lane & 15;
    int quad = lane >> 4;
    int row = tile * 16 + sub;

    floatx4 acc0 = {0.f, 0.f, 0.f, 0.f};
    floatx4 acc1 = {0.f, 0.f, 0.f, 0.f};
    floatx4 acc2 = {0.f, 0.f, 0.f, 0.f};
    floatx4 acc3 = {0.f, 0.f, 0.f, 0.f};

    const _Float16* zrow = (const _Float16*)zm1 + (size_t)row * 64 + quad * 8;
    const _Float16* xrow = (const _Float16*)xh + (size_t)row * 64 + quad * 8;
    const _Float16* wb = (const _Float16*)wbuf1 + (size_t)lane * 8;

    half8 amat[5];
    amat[0] = *(const half8*)(zrow);
    amat[1] = *(const half8*)(zrow + 32);
    amat[2] = *(const half8*)(xrow);
    amat[3] = *(const half8*)(xrow + 32);
    half8 a4 = {0, 0, 0, 0, 0, 0, 0, 0};
    if (quad == 0) {
        a4[0] = ((const _Float16*)mt1)[row];
        a4[1] = (_Float16)tau[row];
    }
    amat[4] = a4;

#pragma unroll
    for (int ks = 0; ks < 5; ++ks) {
        half8 a = amat[ks];
        half8 b0 = *(const half8*)(wb + (size_t)(ks * 4 + 0) * 512);
        half8 b1 = *(const half8*)(wb + (size_t)(ks * 4 + 1) * 512);
        half8 b2 = *(const half8*)(wb + (size_t)(ks * 4 + 2) * 512);
        half8 b3 = *(const half8*)(wb + (size_t)(ks * 4 + 3) * 512);
        acc0 = __builtin_amdgcn_mfma_f32_16x16x32_f16(a, b0, acc0, 0, 0, 0);
        acc1 = __builtin_amdgcn_mfma_f32_16x16x32_f16(a, b1, acc1, 0, 0, 0);
        acc2 = __builtin_amdgcn_mfma_f32_16x16x32_f16(a, b2, acc2, 0, 0, 0);
        acc3 = __builtin_amdgcn_mfma_f32_16x16x32_f16(a, b3, acc3, 0, 0, 0);
    }
    float bv0 = b1l[sub], bv1 = b1l[16 + sub], bv2 = b1l[32 + sub], bv3 = b1l[48 + sub];
#pragma unroll
    for (int reg = 0; reg < 4; ++reg) {
        int r = quad * 4 + reg;
        float v0 = fmaxf(acc0[reg] + bv0, 0.f);
        float v1 = fmaxf(acc1[reg] + bv1, 0.f);
        float v2 = fmaxf(acc2[reg] + bv2, 0.f);
        float v3 = fmaxf(acc3[reg] + bv3, 0.f);
        __half* orow = h1 + (size_t)(tile * 16 + r) * 64;
        orow[sub]      = __float2half(v0);
        orow[16 + sub] = __float2half(v1);
        orow[32 + sub] = __float2half(v2);
        orow[48 + sub] = __float2half(v3);
        unsigned char* orow8 = h1f8 + (size_t)(tile * 16 + r) * 64;
        orow8[sub]      = f_to_f8(v0);
        orow8[16 + sub] = f_to_f8(v1);
        orow8[32 + sub] = f_to_f8(v2);
        orow8[48 + sub] = f_to_f8(v3);
    }
}

__global__ __launch_bounds__(256) void k_gemm2(
    const __half* __restrict__ zm2, const __half* __restrict__ h1,
    const __half* __restrict__ wbuf2, const float* __restrict__ b2l,
    const float* __restrict__ Wfc, const float* __restrict__ bfc,
    float* __restrict__ out, int ntiles) {
    int tile = blockIdx.x * 4 + (threadIdx.x >> 6);
    if (tile >= ntiles) return;
    int lane = threadIdx.x & 63;
    int sub = lane & 15;
    int quad = lane >> 4;
    int row = tile * 16 + sub;

    floatx4 acc0 = {0.f, 0.f, 0.f, 0.f};
    floatx4 acc1 = {0.f, 0.f, 0.f, 0.f};
    floatx4 acc2 = {0.f, 0.f, 0.f, 0.f};
    floatx4 acc3 = {0.f, 0.f, 0.f, 0.f};

    const _Float16* zrow = (const _Float16*)zm2 + (size_t)row * 64 + quad * 8;
    const _Float16* hrow = (const _Float16*)h1 + (size_t)row * 64 + quad * 8;
    const _Float16* wb = (const _Float16*)wbuf2 + (size_t)lane * 8;

    half8 amat[4];
    amat[0] = *(const half8*)(zrow);
    amat[1] = *(const half8*)(zrow + 32);
    amat[2] = *(const half8*)(hrow);
    amat[3] = *(const half8*)(hrow + 32);

#pragma unroll
    for (int ks = 0; ks < 4; ++ks) {
        half8 a = amat[ks];
        half8 b0 = *(const half8*)(wb + (size_t)(ks * 4 + 0) * 512);
        half8 b1 = *(const half8*)(wb + (size_t)(ks * 4 + 1) * 512);
        half8 b2 = *(const half8*)(wb + (size_t)(ks * 4 + 2) * 512);
        half8 b3 = *(const half8*)(wb + (size_t)(ks * 4 + 3) * 512);
        acc0 = __builtin_amdgcn_mfma_f32_16x16x32_f16(a, b0, acc0, 0, 0, 0);
        acc1 = __builtin_amdgcn_mfma_f32_16x16x32_f16(a, b1, acc1, 0, 0, 0);
        acc2 = __builtin_amdgcn_mfma_f32_16x16x32_f16(a, b2, acc2, 0, 0, 0);
        acc3 = __builtin_amdgcn_mfma_f32_16x16x32_f16(a, b3, acc3, 0, 0, 0);
    }
    float bb0 = b2l[sub], bb1 = b2l[16 + sub], bb2 = b2l[32 + sub], bb3 = b2l[48 + sub];
    float wv0 = Wfc[sub], wv1 = Wfc[16 + sub], wv2 = Wfc[32 + sub], wv3 = Wfc[48 + sub];
    float p[4];
#pragma unroll
    for (int reg = 0; reg < 4; ++reg) {
        p[reg] = fmaxf(acc0[reg] + bb0, 0.f) * wv0
               + fmaxf(acc1[reg] + bb1, 0.f) * wv1
               + fmaxf(acc2[reg] + bb2, 0.f) * wv2
               + fmaxf(acc3[reg] + bb3, 0.f) * wv3;
    }
#pragma unroll
    for (int m = 1; m <= 8; m <<= 1) {
#pragma unroll
        for (int reg = 0; reg < 4; ++reg) p[reg] += __shfl_xor(p[reg], m, 64);
    }
    if (sub == 0) {
        float b0 = bfc[0];
#pragma unroll
        for (int reg = 0; reg < 4; ++reg)
            out[tile * 16 + quad * 4 + reg] = p[reg] + b0;
    }
}

extern "C" void kernel_launch(void* const* d_in, const int* in_sizes, int n_in,
                              void* d_out, int out_size, void* d_ws, size_t ws_size,
                              hipStream_t stream) {
    const float* x   = (const float*)d_in[0];
    const int*   ei  = (const int*)d_in[1];
    const float* tau = (const float*)d_in[2];
    const float* W1l = (const float*)d_in[3];
    const float* b1l = (const float*)d_in[4];
    const float* W1r = (const float*)d_in[5];
    const float* W2l = (const float*)d_in[6];
    const float* b2l = (const float*)d_in[7];
    const float* W2r = (const float*)d_in[8];
    const float* Wfc = (const float*)d_in[9];
    const float* bfc = (const float*)d_in[10];
    float* out = (float*)d_out;

    const int N = in_sizes[0] / 64;   // 100000
    const int E = in_sizes[1] / 2;    // 3200000 (== NBLK * PER)
    const int* src = ei;
    const int* dst = ei + E;

    char* w = (char*)d_ws;
    auto take = [&](size_t b) { char* p = w; w += (b + 255) & ~(size_t)255; return p; };
    int*           histT  = (int*)take((size_t)NBKT * NBLK * 4);  // 1.6 MB
    int*           btot   = (int*)take((size_t)NBKT * 4);
    int*           bstart = (int*)take((size_t)(NBKT + 1) * 4);
    int*           binned = (int*)take((size_t)(E + 64) * 4);     // 12.8 MB (+pad)
    int*           nodeoff= (int*)take((size_t)(N + 2) * 4);      // 400 KB
    __half*        xh     = (__half*)take((size_t)N * 64 * 2);    // 12.8 MB
    unsigned char* xf8    = (unsigned char*)take((size_t)N * 64); // 6.4 MB
    __half*        h1     = (__half*)take((size_t)N * 64 * 2);    // 12.8 MB
    unsigned char* h1f8   = (unsigned char*)take((size_t)N * 64); // 6.4 MB
    __half*        zm1    = (__half*)take((size_t)N * 64 * 2);    // 12.8 MB
    __half*        mt1    = (__half*)take((size_t)N * 2);
    __half*        zm2    = (__half*)take((size_t)N * 64 * 2);    // 12.8 MB
    __half*        wbuf1  = (__half*)take(1280 * 8 * 2);          // 20 KB
    __half*        wbuf2  = (__half*)take(1024 * 8 * 2);          // 16 KB

    int n4 = N * 16;                       // float4 elements of x
    int hpblocks = NBLK + 9 + (n4 + 255) / 256;
    int ntiles = N / 16;                   // 6250 (exact)
    int gblocks = (ntiles + 3) / 4;        // 1563
    int ablocks = (N + 7) / 8;             // 12500 aggr blocks (8 nodes each)

    k_histprep<<<hpblocks, 256, 0, stream>>>(dst, histT, E, x, xh, xf8, n4,
                                             W1l, W1r, W2l, W2r, wbuf1, wbuf2);
    k_scanblk <<<NBKT, NBLK, 0, stream>>>(histT, btot);
    k_scanbkt <<<1, 1024, 0, stream>>>(btot, bstart);
    k_scatter <<<NBLK, 256, 0, stream>>>(src, dst, histT, bstart, binned, E);
    k_csr     <<<NBKT, 512, 0, stream>>>(binned, bstart, nodeoff, E, N);
    k_aggrb1  <<<ablocks, AB2, 0, stream>>>(binned, nodeoff, xf8, tau, zm1, mt1, N);
    k_gemm1   <<<gblocks, 256, 0, stream>>>(zm1, mt1, xh, tau, wbuf1, b1l, h1, h1f8, ntiles);
    k_aggrb2  <<<ablocks, AB2, 0, stream>>>(binned, nodeoff, h1f8, zm2, N);
    k_gemm2   <<<gblocks, 256, 0, stream>>>(zm2, h1, wbuf2, b2l, Wfc, bfc, out, ntiles);
}

// Round 10
// 254.553 us; speedup vs baseline: 1.2056x; 1.0199x over previous
//
#include <hip/hip_runtime.h>
#include <hip/hip_bf16.h>
#include <hip/hip_fp16.h>
#include <hip/hip_fp8.h>

// GQNN: 2-layer GraphSAGE (mean aggr) + fc head. N=100k, E=3.2M, d=64/65.
// R25 (resubmit; R9 bench was GPUAcquisitionTimeout — never measured).
// Widen the sort pipeline. R24 post-mortem: aggr at 51us steady with 67%
// occupancy and 4.3TB/s effective on random 64B gathers (~70% of streaming
// ceiling) => near gather roofline; the ~160us non-aggr pipeline (never in
// top-5, all <51us) has ~100us of slack vs its ~40us byte roofline. Suspects:
// k_scatter (256 thr vs 6250 edges/block) and k_csr (512 thr vs ~4096
// edges/bucket). Fix: scatter 256->512 thr (+x2-batched loads), csr 512->1024
// thr (x2-batched), histprep hist pass x2-batched. Aggr kernels IDENTICAL to
// R24 (best measured). If total drops <10us, slack is launch/dependency-bound
// -> fuse next; else one more widening round then declare.

#define BSH 7                    // bucket shift: 128 nodes per bucket
#define NBKT 782                 // ceil(100000 / 128)
#define NBLK 512                 // binning blocks
#define PER 6250                 // edges per scatter block (E/NBLK)
#define CAP 6144                 // bucket edge capacity (mean 4096, sigma 64)
#define AB2 128                  // aggr block threads (2 waves)

typedef _Float16 half8 __attribute__((ext_vector_type(8)));
typedef float floatx4 __attribute__((ext_vector_type(4)));
typedef float floatx2 __attribute__((ext_vector_type(2)));
typedef int intx4 __attribute__((ext_vector_type(4)));

struct h4s { __half2 lo, hi; };  // 8B fp16 row chunk

// ---- fp8 (OCP e4m3) decode/encode via hw instructions ----
#if __has_builtin(__builtin_amdgcn_cvt_pk_f32_fp8)
template <bool HI>
__device__ __forceinline__ float2 f8x2_to_f2(int v) {
    floatx2 r = __builtin_amdgcn_cvt_pk_f32_fp8(v, HI);
    return make_float2(r.x, r.y);
}
#else
template <bool HI>
__device__ __forceinline__ float2 f8x2_to_f2(int v) {
    unsigned short u = HI ? (unsigned short)(((unsigned)v) >> 16)
                          : (unsigned short)(v & 0xFFFF);
    __half2_raw r = __hip_cvt_fp8x2_to_halfraw2((__hip_fp8x2_storage_t)u, __HIP_E4M3);
    return __half22float2(*(__half2*)&r);
}
#endif

#if __has_builtin(__builtin_amdgcn_cvt_pk_fp8_f32)
__device__ __forceinline__ unsigned f4_to_f8x4(float a, float b, float c, float d) {
    int lo = __builtin_amdgcn_cvt_pk_fp8_f32(a, b, 0, false);
    return (unsigned)__builtin_amdgcn_cvt_pk_fp8_f32(c, d, lo, true);
}
__device__ __forceinline__ unsigned char f_to_f8(float a) {
    return (unsigned char)(__builtin_amdgcn_cvt_pk_fp8_f32(a, a, 0, false) & 0xFF);
}
#else
__device__ __forceinline__ unsigned f4_to_f8x4(float a, float b, float c, float d) {
    unsigned lo = (unsigned)__hip_cvt_float2_to_fp8x2(make_float2(a, b), __HIP_SATFINITE, __HIP_E4M3);
    unsigned hi = (unsigned)__hip_cvt_float2_to_fp8x2(make_float2(c, d), __HIP_SATFINITE, __HIP_E4M3);
    return lo | (hi << 16);
}
__device__ __forceinline__ unsigned char f_to_f8(float a) {
    return (unsigned char)__hip_cvt_float_to_fp8(a, __HIP_SATFINITE, __HIP_E4M3);
}
#endif

// ---------------- hist + prep (fused; k-major histT) ----------------
__global__ __launch_bounds__(256) void k_histprep(
    const int* __restrict__ dst, int* __restrict__ histT, int E,
    const float* __restrict__ x, __half* __restrict__ xh,
    unsigned char* __restrict__ xf8, int n4,
    const float* __restrict__ W1l, const float* __restrict__ W1r,
    const float* __restrict__ W2l, const float* __restrict__ W2r,
    __half* __restrict__ wbuf1, __half* __restrict__ wbuf2) {
    if (blockIdx.x < NBLK) {
        __shared__ int h[NBKT];
        for (int i = threadIdx.x; i < NBKT; i += 256) h[i] = 0;
        __syncthreads();
        int lo = blockIdx.x * PER;
        int hi = lo + PER; if (hi > E) hi = E;
        for (int e0 = lo + threadIdx.x; e0 < hi; e0 += 512) {
            int e1 = e0 + 256;
            int d0 = dst[e0];
            int d1 = (e1 < hi) ? dst[e1] : -1;
            atomicAdd(&h[d0 >> BSH], 1);
            if (d1 >= 0) atomicAdd(&h[d1 >> BSH], 1);
        }
        __syncthreads();
        for (int k = threadIdx.x; k < NBKT; k += 256)
            histT[k * NBLK + blockIdx.x] = h[k];
    } else if (blockIdx.x < NBLK + 9) {
        int idx = (blockIdx.x - NBLK) * 256 + threadIdx.x;
        if (idx < 1280) {
            int lane = idx & 63;
            int nt = (idx >> 6) & 3;
            int kstep = idx >> 8;
            int col = nt * 16 + (lane & 15);
            int kbase = kstep * 32 + (lane >> 4) * 8;
#pragma unroll
            for (int j = 0; j < 8; ++j) {
                int k = kbase + j;
                float v;
                if (k < 64)        v = W1l[k * 64 + col];
                else if (k < 128)  v = W1r[(k - 64) * 64 + col];
                else if (k == 128) v = W1l[64 * 64 + col];
                else if (k == 129) v = W1r[64 * 64 + col];
                else v = 0.f;
                wbuf1[(size_t)idx * 8 + j] = __float2half(v);
            }
        } else if (idx < 1280 + 1024) {
            int i2 = idx - 1280;
            int lane = i2 & 63;
            int nt = (i2 >> 6) & 3;
            int kstep = i2 >> 8;
            int col = nt * 16 + (lane & 15);
            int kbase = kstep * 32 + (lane >> 4) * 8;
#pragma unroll
            for (int j = 0; j < 8; ++j) {
                int k = kbase + j;
                float v = (k < 64) ? W2l[k * 64 + col] : W2r[(k - 64) * 64 + col];
                wbuf2[(size_t)i2 * 8 + j] = __float2half(v);
            }
        }
    } else {
        int i = (blockIdx.x - NBLK - 9) * 256 + threadIdx.x;
        if (i < n4) {
            float4 v = ((const float4*)x)[i];
            ((__half2*)xh)[2 * i]     = __floats2half2_rn(v.x, v.y);
            ((__half2*)xh)[2 * i + 1] = __floats2half2_rn(v.z, v.w);
            ((unsigned*)xf8)[i] = f4_to_f8x4(v.x, v.y, v.z, v.w);
        }
    }
}

// ---------------- scans ----------------

__global__ __launch_bounds__(NBLK) void k_scanblk(int* __restrict__ histT,
                                                  int* __restrict__ btot) {
    __shared__ int s[NBLK];
    int k = blockIdx.x, t = threadIdx.x;
    int v = histT[k * NBLK + t];
    s[t] = v;
    __syncthreads();
    for (int off = 1; off < NBLK; off <<= 1) {
        int u = (t >= off) ? s[t - off] : 0;
        __syncthreads();
        s[t] += u;
        __syncthreads();
    }
    histT[k * NBLK + t] = s[t] - v;
    if (t == NBLK - 1) btot[k] = s[t];
}

__global__ __launch_bounds__(1024) void k_scanbkt(const int* __restrict__ btot,
                                                  int* __restrict__ bstart) {
    __shared__ int s[1024];
    int t = threadIdx.x;
    int v = (t < NBKT) ? btot[t] : 0;
    s[t] = v;
    __syncthreads();
    for (int off = 1; off < 1024; off <<= 1) {
        int u = (t >= off) ? s[t - off] : 0;
        __syncthreads();
        s[t] += u;
        __syncthreads();
    }
    if (t < NBKT) bstart[t] = s[t] - v;
    if (t == NBKT - 1) bstart[NBKT] = s[t];
}

// ---------------- scatter: LDS counting sort (512 thr) ----------------
__global__ __launch_bounds__(512) void k_scatter(const int* __restrict__ src,
                                                 const int* __restrict__ dst,
                                                 const int* __restrict__ histT,
                                                 const int* __restrict__ bstart,
                                                 int* __restrict__ binned, int E) {
    __shared__ int sorted[PER];          // 25 KB
    __shared__ int lstart[NBKT + 1];
    __shared__ int cur[NBKT];
    __shared__ int gst[NBKT];
    __shared__ int tsum[512];
    int b = blockIdx.x, t = threadIdx.x;
    int base = b * PER;
    int blen = E - base; if (blen > PER) blen = PER;
    int hiE = base + blen;

    for (int k = t; k < NBKT; k += 512) lstart[k] = 0;
    __syncthreads();
    for (int e0 = base + t; e0 < hiE; e0 += 1024) {
        int e1 = e0 + 512;
        int d0 = dst[e0];
        int d1 = (e1 < hiE) ? dst[e1] : -1;
        atomicAdd(&lstart[d0 >> BSH], 1);
        if (d1 >= 0) atomicAdd(&lstart[d1 >> BSH], 1);
    }
    __syncthreads();
    int c0 = 0;
    int i0 = t * 2;
#pragma unroll
    for (int j = 0; j < 2; ++j)
        if (i0 + j < NBKT) c0 += lstart[i0 + j];
    tsum[t] = c0;
    __syncthreads();
    for (int off = 1; off < 512; off <<= 1) {
        int u = (t >= off) ? tsum[t - off] : 0;
        __syncthreads();
        tsum[t] += u;
        __syncthreads();
    }
    int running = tsum[t] - c0;
    __syncthreads();
#pragma unroll
    for (int j = 0; j < 2; ++j) {
        int i = i0 + j;
        if (i < NBKT) {
            int v = lstart[i];
            lstart[i] = running;
            running += v;
        }
    }
    __syncthreads();
    if (t == 0) lstart[NBKT] = blen;
    for (int k = t; k < NBKT; k += 512) {
        cur[k] = lstart[k];
        gst[k] = bstart[k] + histT[k * NBLK + b];
    }
    __syncthreads();
    for (int e = base + t; e < hiE; e += 512) {
        int d = dst[e], s = src[e];
        int pos = atomicAdd(&cur[d >> BSH], 1);
        sorted[pos] = (s << BSH) | (d & ((1 << BSH) - 1));
    }
    __syncthreads();
    int qw = t >> 4, ql = t & 15;        // 32 quarter-wave groups
    for (int k = qw; k < NBKT; k += 32) {
        int st = lstart[k];
        int ln = lstart[k + 1] - st;
        int gd = gst[k];
        for (int i = ql; i < ln; i += 16)
            binned[gd + i] = sorted[st + i];
    }
}

// ---------------- CSR finalize: sort each bucket by node (1024 thr) ---------
__global__ __launch_bounds__(1024) void k_csr(int* __restrict__ binned,
                                              const int* __restrict__ bstart,
                                              int* __restrict__ nodeoff,
                                              int E, int N) {
    __shared__ int cnt[128], sarr[128], cur[128];
    __shared__ int sorted[CAP];          // 24 KB
    int k = blockIdx.x, t = threadIdx.x;
    int lo = bstart[k], hi = bstart[k + 1];
    if (t < 128) cnt[t] = 0;
    __syncthreads();
    for (int eb = lo; eb < hi; eb += 1024 * 2) {
        int e0 = eb + t, e1 = e0 + 1024;
        int p0 = (e0 < hi) ? binned[e0] : -1;
        int p1 = (e1 < hi) ? binned[e1] : -1;
        if (p0 >= 0) atomicAdd(&cnt[p0 & 127], 1);
        if (p1 >= 0) atomicAdd(&cnt[p1 & 127], 1);
    }
    __syncthreads();
    if (t < 128) sarr[t] = cnt[t];
    __syncthreads();
    for (int off = 1; off < 128; off <<= 1) {
        int u = 0;
        if (t < 128 && t >= off) u = sarr[t - off];
        __syncthreads();
        if (t < 128) sarr[t] += u;
        __syncthreads();
    }
    if (t < 128) {
        int excl = sarr[t] - cnt[t];
        cur[t] = excl;
        int node = (k << BSH) + t;
        if (node < N) nodeoff[node] = lo + excl;
    }
    if (k == NBKT - 1 && t == 0) nodeoff[N] = E;
    __syncthreads();
    for (int eb = lo; eb < hi; eb += 1024 * 2) {
        int e0 = eb + t, e1 = e0 + 1024;
        int p0 = (e0 < hi) ? binned[e0] : -1;
        int p1 = (e1 < hi) ? binned[e1] : -1;
        if (p0 >= 0) { int pos = atomicAdd(&cur[p0 & 127], 1); if (pos < CAP) sorted[pos] = p0 >> BSH; }
        if (p1 >= 0) { int pos = atomicAdd(&cur[p1 & 127], 1); if (pos < CAP) sorted[pos] = p1 >> BSH; }
    }
    __syncthreads();
    int len = hi - lo; if (len > CAP) len = CAP;
    for (int i = t; i < len; i += 1024)
        binned[lo + i] = sorted[i];
}

// ---------------- aggregation (no LDS; 2-wave blocks, 8 nodes each) --------
// IDENTICAL to R24 (best measured): quarter q owns one node; lane
// (ch=c>>2, g=c&3) loads 16B chunk ch of neighbor slot 4j+g via dwordx4
// (16 rows/instr). Straight-line rounds, intx4 AND-mask, scalar-select
// sanitize, depth-2 index prefetch.

// zm1[node][64] = mean_x (fp16); mt1[node] = mean_tau (fp16)
__global__ __launch_bounds__(AB2, 8) void k_aggrb1(
    const int* __restrict__ nbr, const int* __restrict__ nodeoff,
    const unsigned char* __restrict__ xf8, const float* __restrict__ tau,
    __half* __restrict__ zm1, __half* __restrict__ mt1, int N) {
    int t = threadIdx.x;
    int lane = t & 63;
    int q = lane >> 4;
    int c = lane & 15;
    int g = c & 3;                      // neighbor-slot within a group of 4
    int ch = c >> 2;                    // 16B chunk index within the 64B row
    unsigned cb = (unsigned)(ch << 4);  // chunk byte offset
    const char* xb = (const char*)xf8;
    int nb = blockIdx.x << 3;           // 8 nodes per block (2 waves x 4)

    {
        int p = t >> 6;                 // wave id 0/1
        int ld = (p << 2) + q;
        int node = nb + ld;
        int off0 = 0, off1 = 0;
        if (node < N) { off0 = nodeoff[node]; off1 = nodeoff[node + 1]; }
        int d = off1 - off0;
        int dm = d;
        dm = max(dm, __shfl_xor(dm, 16, 64));
        dm = max(dm, __shfl_xor(dm, 32, 64));
        float4 A0 = {0.f, 0.f, 0.f, 0.f}, A1 = A0, A2 = A0, A3 = A0;
        float sumtau = 0.f;
        // prefetch round-0 index words (binned padded: overrun reads safe)
        int base0 = off0 + g;
        int nx0 = nbr[base0];
        int nx1 = nbr[base0 + 4];
        int nx2 = nbr[base0 + 8];
        int nx3 = nbr[base0 + 12];
        for (int base = 0; base < dm; base += 16) {
            int s0 = base + g;
            bool v0 = s0 < d, v1 = s0 + 4 < d, v2 = s0 + 8 < d, v3 = s0 + 12 < d;
            int cu0 = nx0, cu1 = nx1, cu2 = nx2, cu3 = nx3;
            // prefetch next round's index words (pipeline depth 2)
            int bn = base0 + base + 16;
            nx0 = nbr[bn];
            nx1 = nbr[bn + 4];
            nx2 = nbr[bn + 8];
            nx3 = nbr[bn + 12];
            int sx0 = v0 ? cu0 : 0;     // sanitize gather row
            int sx1 = v1 ? cu1 : 0;
            int sx2 = v2 ? cu2 : 0;
            int sx3 = v3 ? cu3 : 0;
            intx4 r0 = *(const intx4*)(xb + (((unsigned)sx0 << 6) + cb));
            intx4 r1 = *(const intx4*)(xb + (((unsigned)sx1 << 6) + cb));
            intx4 r2 = *(const intx4*)(xb + (((unsigned)sx2 << 6) + cb));
            intx4 r3 = *(const intx4*)(xb + (((unsigned)sx3 << 6) + cb));
            float ta0 = tau[sx0], ta1 = tau[sx1], ta2 = tau[sx2], ta3 = tau[sx3];
            sumtau += (v0 ? ta0 : 0.f) + (v1 ? ta1 : 0.f)
                    + (v2 ? ta2 : 0.f) + (v3 ? ta3 : 0.f);
            int m0 = v0 ? -1 : 0, m1 = v1 ? -1 : 0, m2 = v2 ? -1 : 0, m3 = v3 ? -1 : 0;
            r0 &= (intx4){m0, m0, m0, m0};
            r1 &= (intx4){m1, m1, m1, m1};
            r2 &= (intx4){m2, m2, m2, m2};
            r3 &= (intx4){m3, m3, m3, m3};
            {
                float2 l0 = f8x2_to_f2<false>(r0.x), h0 = f8x2_to_f2<true>(r0.x);
                float2 l1 = f8x2_to_f2<false>(r0.y), h1v = f8x2_to_f2<true>(r0.y);
                float2 l2 = f8x2_to_f2<false>(r0.z), h2v = f8x2_to_f2<true>(r0.z);
                float2 l3 = f8x2_to_f2<false>(r0.w), h3v = f8x2_to_f2<true>(r0.w);
                A0.x += l0.x; A0.y += l0.y; A0.z += h0.x; A0.w += h0.y;
                A1.x += l1.x; A1.y += l1.y; A1.z += h1v.x; A1.w += h1v.y;
                A2.x += l2.x; A2.y += l2.y; A2.z += h2v.x; A2.w += h2v.y;
                A3.x += l3.x; A3.y += l3.y; A3.z += h3v.x; A3.w += h3v.y;
            }
            {
                float2 l0 = f8x2_to_f2<false>(r1.x), h0 = f8x2_to_f2<true>(r1.x);
                float2 l1 = f8x2_to_f2<false>(r1.y), h1v = f8x2_to_f2<true>(r1.y);
                float2 l2 = f8x2_to_f2<false>(r1.z), h2v = f8x2_to_f2<true>(r1.z);
                float2 l3 = f8x2_to_f2<false>(r1.w), h3v = f8x2_to_f2<true>(r1.w);
                A0.x += l0.x; A0.y += l0.y; A0.z += h0.x; A0.w += h0.y;
                A1.x += l1.x; A1.y += l1.y; A1.z += h1v.x; A1.w += h1v.y;
                A2.x += l2.x; A2.y += l2.y; A2.z += h2v.x; A2.w += h2v.y;
                A3.x += l3.x; A3.y += l3.y; A3.z += h3v.x; A3.w += h3v.y;
            }
            {
                float2 l0 = f8x2_to_f2<false>(r2.x), h0 = f8x2_to_f2<true>(r2.x);
                float2 l1 = f8x2_to_f2<false>(r2.y), h1v = f8x2_to_f2<true>(r2.y);
                float2 l2 = f8x2_to_f2<false>(r2.z), h2v = f8x2_to_f2<true>(r2.z);
                float2 l3 = f8x2_to_f2<false>(r2.w), h3v = f8x2_to_f2<true>(r2.w);
                A0.x += l0.x; A0.y += l0.y; A0.z += h0.x; A0.w += h0.y;
                A1.x += l1.x; A1.y += l1.y; A1.z += h1v.x; A1.w += h1v.y;
                A2.x += l2.x; A2.y += l2.y; A2.z += h2v.x; A2.w += h2v.y;
                A3.x += l3.x; A3.y += l3.y; A3.z += h3v.x; A3.w += h3v.y;
            }
            {
                float2 l0 = f8x2_to_f2<false>(r3.x), h0 = f8x2_to_f2<true>(r3.x);
                float2 l1 = f8x2_to_f2<false>(r3.y), h1v = f8x2_to_f2<true>(r3.y);
                float2 l2 = f8x2_to_f2<false>(r3.z), h2v = f8x2_to_f2<true>(r3.z);
                float2 l3 = f8x2_to_f2<false>(r3.w), h3v = f8x2_to_f2<true>(r3.w);
                A0.x += l0.x; A0.y += l0.y; A0.z += h0.x; A0.w += h0.y;
                A1.x += l1.x; A1.y += l1.y; A1.z += h1v.x; A1.w += h1v.y;
                A2.x += l2.x; A2.y += l2.y; A2.z += h2v.x; A2.w += h2v.y;
                A3.x += l3.x; A3.y += l3.y; A3.z += h3v.x; A3.w += h3v.y;
            }
        }
        // combine the 4 neighbor-groups: butterfly over g (lanes c^1, c^2);
        // every lane ends with the full sum, so all 16 lanes write below.
#pragma unroll
        for (int off = 1; off <= 2; off <<= 1) {
            A0.x += __shfl_xor(A0.x, off, 64); A0.y += __shfl_xor(A0.y, off, 64);
            A0.z += __shfl_xor(A0.z, off, 64); A0.w += __shfl_xor(A0.w, off, 64);
            A1.x += __shfl_xor(A1.x, off, 64); A1.y += __shfl_xor(A1.y, off, 64);
            A1.z += __shfl_xor(A1.z, off, 64); A1.w += __shfl_xor(A1.w, off, 64);
            A2.x += __shfl_xor(A2.x, off, 64); A2.y += __shfl_xor(A2.y, off, 64);
            A2.z += __shfl_xor(A2.z, off, 64); A2.w += __shfl_xor(A2.w, off, 64);
            A3.x += __shfl_xor(A3.x, off, 64); A3.y += __shfl_xor(A3.y, off, 64);
            A3.z += __shfl_xor(A3.z, off, 64); A3.w += __shfl_xor(A3.w, off, 64);
            sumtau += __shfl_xor(sumtau, off, 64);
        }
        float inv = 1.f / fmaxf((float)d, 1.f);
        if (node < N) {
            // lane (ch,g) writes dword g of chunk ch = cols ch*16 + g*4 .. +4
            float4 Aw = (g == 0) ? A0 : ((g == 1) ? A1 : ((g == 2) ? A2 : A3));
            h4s o;
            o.lo = __floats2half2_rn(Aw.x * inv, Aw.y * inv);
            o.hi = __floats2half2_rn(Aw.z * inv, Aw.w * inv);
            *(h4s*)(zm1 + (size_t)node * 64 + (ch << 4) + (g << 2)) = o;
            if (c == 0) mt1[node] = __float2half(sumtau * inv);
        }
    }
}

// zm2[node][64] = mean_h1 (fp16), gathered from h1f8
__global__ __launch_bounds__(AB2, 8) void k_aggrb2(
    const int* __restrict__ nbr, const int* __restrict__ nodeoff,
    const unsigned char* __restrict__ h1f8, __half* __restrict__ zm2, int N) {
    int t = threadIdx.x;
    int lane = t & 63;
    int q = lane >> 4;
    int c = lane & 15;
    int g = c & 3;
    int ch = c >> 2;
    unsigned cb = (unsigned)(ch << 4);
    const char* hb = (const char*)h1f8;
    int nb = blockIdx.x << 3;

    {
        int p = t >> 6;
        int ld = (p << 2) + q;
        int node = nb + ld;
        int off0 = 0, off1 = 0;
        if (node < N) { off0 = nodeoff[node]; off1 = nodeoff[node + 1]; }
        int d = off1 - off0;
        int dm = d;
        dm = max(dm, __shfl_xor(dm, 16, 64));
        dm = max(dm, __shfl_xor(dm, 32, 64));
        float4 A0 = {0.f, 0.f, 0.f, 0.f}, A1 = A0, A2 = A0, A3 = A0;
        int base0 = off0 + g;
        int nx0 = nbr[base0];
        int nx1 = nbr[base0 + 4];
        int nx2 = nbr[base0 + 8];
        int nx3 = nbr[base0 + 12];
        for (int base = 0; base < dm; base += 16) {
            int s0 = base + g;
            bool v0 = s0 < d, v1 = s0 + 4 < d, v2 = s0 + 8 < d, v3 = s0 + 12 < d;
            int cu0 = nx0, cu1 = nx1, cu2 = nx2, cu3 = nx3;
            int bn = base0 + base + 16;
            nx0 = nbr[bn];
            nx1 = nbr[bn + 4];
            nx2 = nbr[bn + 8];
            nx3 = nbr[bn + 12];
            int sx0 = v0 ? cu0 : 0;
            int sx1 = v1 ? cu1 : 0;
            int sx2 = v2 ? cu2 : 0;
            int sx3 = v3 ? cu3 : 0;
            intx4 r0 = *(const intx4*)(hb + (((unsigned)sx0 << 6) + cb));
            intx4 r1 = *(const intx4*)(hb + (((unsigned)sx1 << 6) + cb));
            intx4 r2 = *(const intx4*)(hb + (((unsigned)sx2 << 6) + cb));
            intx4 r3 = *(const intx4*)(hb + (((unsigned)sx3 << 6) + cb));
            int m0 = v0 ? -1 : 0, m1 = v1 ? -1 : 0, m2 = v2 ? -1 : 0, m3 = v3 ? -1 : 0;
            r0 &= (intx4){m0, m0, m0, m0};
            r1 &= (intx4){m1, m1, m1, m1};
            r2 &= (intx4){m2, m2, m2, m2};
            r3 &= (intx4){m3, m3, m3, m3};
            {
                float2 l0 = f8x2_to_f2<false>(r0.x), h0 = f8x2_to_f2<true>(r0.x);
                float2 l1 = f8x2_to_f2<false>(r0.y), h1v = f8x2_to_f2<true>(r0.y);
                float2 l2 = f8x2_to_f2<false>(r0.z), h2v = f8x2_to_f2<true>(r0.z);
                float2 l3 = f8x2_to_f2<false>(r0.w), h3v = f8x2_to_f2<true>(r0.w);
                A0.x += l0.x; A0.y += l0.y; A0.z += h0.x; A0.w += h0.y;
                A1.x += l1.x; A1.y += l1.y; A1.z += h1v.x; A1.w += h1v.y;
                A2.x += l2.x; A2.y += l2.y; A2.z += h2v.x; A2.w += h2v.y;
                A3.x += l3.x; A3.y += l3.y; A3.z += h3v.x; A3.w += h3v.y;
            }
            {
                float2 l0 = f8x2_to_f2<false>(r1.x), h0 = f8x2_to_f2<true>(r1.x);
                float2 l1 = f8x2_to_f2<false>(r1.y), h1v = f8x2_to_f2<true>(r1.y);
                float2 l2 = f8x2_to_f2<false>(r1.z), h2v = f8x2_to_f2<true>(r1.z);
                float2 l3 = f8x2_to_f2<false>(r1.w), h3v = f8x2_to_f2<true>(r1.w);
                A0.x += l0.x; A0.y += l0.y; A0.z += h0.x; A0.w += h0.y;
                A1.x += l1.x; A1.y += l1.y; A1.z += h1v.x; A1.w += h1v.y;
                A2.x += l2.x; A2.y += l2.y; A2.z += h2v.x; A2.w += h2v.y;
                A3.x += l3.x; A3.y += l3.y; A3.z += h3v.x; A3.w += h3v.y;
            }
            {
                float2 l0 = f8x2_to_f2<false>(r2.x), h0 = f8x2_to_f2<true>(r2.x);
                float2 l1 = f8x2_to_f2<false>(r2.y), h1v = f8x2_to_f2<true>(r2.y);
                float2 l2 = f8x2_to_f2<false>(r2.z), h2v = f8x2_to_f2<true>(r2.z);
                float2 l3 = f8x2_to_f2<false>(r2.w), h3v = f8x2_to_f2<true>(r2.w);
                A0.x += l0.x; A0.y += l0.y; A0.z += h0.x; A0.w += h0.y;
                A1.x += l1.x; A1.y += l1.y; A1.z += h1v.x; A1.w += h1v.y;
                A2.x += l2.x; A2.y += l2.y; A2.z += h2v.x; A2.w += h2v.y;
                A3.x += l3.x; A3.y += l3.y; A3.z += h3v.x; A3.w += h3v.y;
            }
            {
                float2 l0 = f8x2_to_f2<false>(r3.x), h0 = f8x2_to_f2<true>(r3.x);
                float2 l1 = f8x2_to_f2<false>(r3.y), h1v = f8x2_to_f2<true>(r3.y);
                float2 l2 = f8x2_to_f2<false>(r3.z), h2v = f8x2_to_f2<true>(r3.z);
                float2 l3 = f8x2_to_f2<false>(r3.w), h3v = f8x2_to_f2<true>(r3.w);
                A0.x += l0.x; A0.y += l0.y; A0.z += h0.x; A0.w += h0.y;
                A1.x += l1.x; A1.y += l1.y; A1.z += h1v.x; A1.w += h1v.y;
                A2.x += l2.x; A2.y += l2.y; A2.z += h2v.x; A2.w += h2v.y;
                A3.x += l3.x; A3.y += l3.y; A3.z += h3v.x; A3.w += h3v.y;
            }
        }
#pragma unroll
        for (int off = 1; off <= 2; off <<= 1) {
            A0.x += __shfl_xor(A0.x, off, 64); A0.y += __shfl_xor(A0.y, off, 64);
            A0.z += __shfl_xor(A0.z, off, 64); A0.w += __shfl_xor(A0.w, off, 64);
            A1.x += __shfl_xor(A1.x, off, 64); A1.y += __shfl_xor(A1.y, off, 64);
            A1.z += __shfl_xor(A1.z, off, 64); A1.w += __shfl_xor(A1.w, off, 64);
            A2.x += __shfl_xor(A2.x, off, 64); A2.y += __shfl_xor(A2.y, off, 64);
            A2.z += __shfl_xor(A2.z, off, 64); A2.w += __shfl_xor(A2.w, off, 64);
            A3.x += __shfl_xor(A3.x, off, 64); A3.y += __shfl_xor(A3.y, off, 64);
            A3.z += __shfl_xor(A3.z, off, 64); A3.w += __shfl_xor(A3.w, off, 64);
        }
        float inv = 1.f / fmaxf((float)d, 1.f);
        if (node < N) {
            float4 Aw = (g == 0) ? A0 : ((g == 1) ? A1 : ((g == 2) ? A2 : A3));
            h4s o;
            o.lo = __floats2half2_rn(Aw.x * inv, Aw.y * inv);
            o.hi = __floats2half2_rn(Aw.z * inv, Aw.w * inv);
            *(h4s*)(zm2 + (size_t)node * 64 + (ch << 4) + (g << 2)) = o;
        }
    }
}

// ---------------- MFMA GEMM kernels (unchanged from R13) ----------------

__global__ __launch_bounds__(256) void k_gemm1(
    const __half* __restrict__ zm1, const __half* __restrict__ mt1,
    const __half* __restrict__ xh, const float* __restrict__ tau,
    const __half* __restrict__ wbuf1, const float* __restrict__ b1l,
    __half* __restrict__ h1, unsigned char* __restrict__ h1f8, int ntiles) {
    int tile = blockIdx.x * 4 + (threadIdx.x >> 6);
    if (tile >= ntiles) return;
    int lane = threadIdx.x & 63;
    int sub = lane & 15;
    int quad = lane >> 4;
    int row = tile * 16 + sub;

    floatx4 acc0 = {0.f, 0.f, 0.f, 0.f};
    floatx4 acc1 = {0.f, 0.f, 0.f, 0.f};
    floatx4 acc2 = {0.f, 0.f, 0.f, 0.f};
    floatx4 acc3 = {0.f, 0.f, 0.f, 0.f};

    const _Float16* zrow = (const _Float16*)zm1 + (size_t)row * 64 + quad * 8;
    const _Float16* xrow = (const _Float16*)xh + (size_t)row * 64 + quad * 8;
    const _Float16* wb = (const _Float16*)wbuf1 + (size_t)lane * 8;

    half8 amat[5];
    amat[0] = *(const half8*)(zrow);
    amat[1] = *(const half8*)(zrow + 32);
    amat[2] = *(const half8*)(xrow);
    amat[3] = *(const half8*)(xrow + 32);
    half8 a4 = {0, 0, 0, 0, 0, 0, 0, 0};
    if (quad == 0) {
        a4[0] = ((const _Float16*)mt1)[row];
        a4[1] = (_Float16)tau[row];
    }
    amat[4] = a4;

#pragma unroll
    for (int ks = 0; ks < 5; ++ks) {
        half8 a = amat[ks];
        half8 b0 = *(const half8*)(wb + (size_t)(ks * 4 + 0) * 512);
        half8 b1 = *(const half8*)(wb + (size_t)(ks * 4 + 1) * 512);
        half8 b2 = *(const half8*)(wb + (size_t)(ks * 4 + 2) * 512);
        half8 b3 = *(const half8*)(wb + (size_t)(ks * 4 + 3) * 512);
        acc0 = __builtin_amdgcn_mfma_f32_16x16x32_f16(a, b0, acc0, 0, 0, 0);
        acc1 = __builtin_amdgcn_mfma_f32_16x16x32_f16(a, b1, acc1, 0, 0, 0);
        acc2 = __builtin_amdgcn_mfma_f32_16x16x32_f16(a, b2, acc2, 0, 0, 0);
        acc3 = __builtin_amdgcn_mfma_f32_16x16x32_f16(a, b3, acc3, 0, 0, 0);
    }
    float bv0 = b1l[sub], bv1 = b1l[16 + sub], bv2 = b1l[32 + sub], bv3 = b1l[48 + sub];
#pragma unroll
    for (int reg = 0; reg < 4; ++reg) {
        int r = quad * 4 + reg;
        float v0 = fmaxf(acc0[reg] + bv0, 0.f);
        float v1 = fmaxf(acc1[reg] + bv1, 0.f);
        float v2 = fmaxf(acc2[reg] + bv2, 0.f);
        float v3 = fmaxf(acc3[reg] + bv3, 0.f);
        __half* orow = h1 + (size_t)(tile * 16 + r) * 64;
        orow[sub]      = __float2half(v0);
        orow[16 + sub] = __float2half(v1);
        orow[32 + sub] = __float2half(v2);
        orow[48 + sub] = __float2half(v3);
        unsigned char* orow8 = h1f8 + (size_t)(tile * 16 + r) * 64;
        orow8[sub]      = f_to_f8(v0);
        orow8[16 + sub] = f_to_f8(v1);
        orow8[32 + sub] = f_to_f8(v2);
        orow8[48 + sub] = f_to_f8(v3);
    }
}

__global__ __launch_bounds__(256) void k_gemm2(
    const __half* __restrict__ zm2, const __half* __restrict__ h1,
    const __half* __restrict__ wbuf2, const float* __restrict__ b2l,
    const float* __restrict__ Wfc, const float* __restrict__ bfc,
    float* __restrict__ out, int ntiles) {
    int tile = blockIdx.x * 4 + (threadIdx.x >> 6);
    if (tile >= ntiles) return;
    int lane = threadIdx.x & 63;
    int sub = lane & 15;
    int quad = lane >> 4;
    int row = tile * 16 + sub;

    floatx4 acc0 = {0.f, 0.f, 0.f, 0.f};
    floatx4 acc1 = {0.f, 0.f, 0.f, 0.f};
    floatx4 acc2 = {0.f, 0.f, 0.f, 0.f};
    floatx4 acc3 = {0.f, 0.f, 0.f, 0.f};

    const _Float16* zrow = (const _Float16*)zm2 + (size_t)row * 64 + quad * 8;
    const _Float16* hrow = (const _Float16*)h1 + (size_t)row * 64 + quad * 8;
    const _Float16* wb = (const _Float16*)wbuf2 + (size_t)lane * 8;

    half8 amat[4];
    amat[0] = *(const half8*)(zrow);
    amat[1] = *(const half8*)(zrow + 32);
    amat[2] = *(const half8*)(hrow);
    amat[3] = *(const half8*)(hrow + 32);

#pragma unroll
    for (int ks = 0; ks < 4; ++ks) {
        half8 a = amat[ks];
        half8 b0 = *(const half8*)(wb + (size_t)(ks * 4 + 0) * 512);
        half8 b1 = *(const half8*)(wb + (size_t)(ks * 4 + 1) * 512);
        half8 b2 = *(const half8*)(wb + (size_t)(ks * 4 + 2) * 512);
        half8 b3 = *(const half8*)(wb + (size_t)(ks * 4 + 3) * 512);
        acc0 = __builtin_amdgcn_mfma_f32_16x16x32_f16(a, b0, acc0, 0, 0, 0);
        acc1 = __builtin_amdgcn_mfma_f32_16x16x32_f16(a, b1, acc1, 0, 0, 0);
        acc2 = __builtin_amdgcn_mfma_f32_16x16x32_f16(a, b2, acc2, 0, 0, 0);
        acc3 = __builtin_amdgcn_mfma_f32_16x16x32_f16(a, b3, acc3, 0, 0, 0);
    }
    float bb0 = b2l[sub], bb1 = b2l[16 + sub], bb2 = b2l[32 + sub], bb3 = b2l[48 + sub];
    float wv0 = Wfc[sub], wv1 = Wfc[16 + sub], wv2 = Wfc[32 + sub], wv3 = Wfc[48 + sub];
    float p[4];
#pragma unroll
    for (int reg = 0; reg < 4; ++reg) {
        p[reg] = fmaxf(acc0[reg] + bb0, 0.f) * wv0
               + fmaxf(acc1[reg] + bb1, 0.f) * wv1
               + fmaxf(acc2[reg] + bb2, 0.f) * wv2
               + fmaxf(acc3[reg] + bb3, 0.f) * wv3;
    }
#pragma unroll
    for (int m = 1; m <= 8; m <<= 1) {
#pragma unroll
        for (int reg = 0; reg < 4; ++reg) p[reg] += __shfl_xor(p[reg], m, 64);
    }
    if (sub == 0) {
        float b0 = bfc[0];
#pragma unroll
        for (int reg = 0; reg < 4; ++reg)
            out[tile * 16 + quad * 4 + reg] = p[reg] + b0;
    }
}

extern "C" void kernel_launch(void* const* d_in, const int* in_sizes, int n_in,
                              void* d_out, int out_size, void* d_ws, size_t ws_size,
                              hipStream_t stream) {
    const float* x   = (const float*)d_in[0];
    const int*   ei  = (const int*)d_in[1];
    const float* tau = (const float*)d_in[2];
    const float* W1l = (const float*)d_in[3];
    const float* b1l = (const float*)d_in[4];
    const float* W1r = (const float*)d_in[5];
    const float* W2l = (const float*)d_in[6];
    const float* b2l = (const float*)d_in[7];
    const float* W2r = (const float*)d_in[8];
    const float* Wfc = (const float*)d_in[9];
    const float* bfc = (const float*)d_in[10];
    float* out = (float*)d_out;

    const int N = in_sizes[0] / 64;   // 100000
    const int E = in_sizes[1] / 2;    // 3200000 (== NBLK * PER)
    const int* src = ei;
    const int* dst = ei + E;

    char* w = (char*)d_ws;
    auto take = [&](size_t b) { char* p = w; w += (b + 255) & ~(size_t)255; return p; };
    int*           histT  = (int*)take((size_t)NBKT * NBLK * 4);  // 1.6 MB
    int*           btot   = (int*)take((size_t)NBKT * 4);
    int*           bstart = (int*)take((size_t)(NBKT + 1) * 4);
    int*           binned = (int*)take((size_t)(E + 64) * 4);     // 12.8 MB (+pad)
    int*           nodeoff= (int*)take((size_t)(N + 2) * 4);      // 400 KB
    __half*        xh     = (__half*)take((size_t)N * 64 * 2);    // 12.8 MB
    unsigned char* xf8    = (unsigned char*)take((size_t)N * 64); // 6.4 MB
    __half*        h1     = (__half*)take((size_t)N * 64 * 2);    // 12.8 MB
    unsigned char* h1f8   = (unsigned char*)take((size_t)N * 64); // 6.4 MB
    __half*        zm1    = (__half*)take((size_t)N * 64 * 2);    // 12.8 MB
    __half*        mt1    = (__half*)take((size_t)N * 2);
    __half*        zm2    = (__half*)take((size_t)N * 64 * 2);    // 12.8 MB
    __half*        wbuf1  = (__half*)take(1280 * 8 * 2);          // 20 KB
    __half*        wbuf2  = (__half*)take(1024 * 8 * 2);          // 16 KB

    int n4 = N * 16;                       // float4 elements of x
    int hpblocks = NBLK + 9 + (n4 + 255) / 256;
    int ntiles = N / 16;                   // 6250 (exact)
    int gblocks = (ntiles + 3) / 4;        // 1563
    int ablocks = (N + 7) / 8;             // 12500 aggr blocks (8 nodes each)

    k_histprep<<<hpblocks, 256, 0, stream>>>(dst, histT, E, x, xh, xf8, n4,
                                             W1l, W1r, W2l, W2r, wbuf1, wbuf2);
    k_scanblk <<<NBKT, NBLK, 0, stream>>>(histT, btot);
    k_scanbkt <<<1, 1024, 0, stream>>>(btot, bstart);
    k_scatter <<<NBLK, 512, 0, stream>>>(src, dst, histT, bstart, binned, E);
    k_csr     <<<NBKT, 1024, 0, stream>>>(binned, bstart, nodeoff, E, N);
    k_aggrb1  <<<ablocks, AB2, 0, stream>>>(binned, nodeoff, xf8, tau, zm1, mt1, N);
    k_gemm1   <<<gblocks, 256, 0, stream>>>(zm1, mt1, xh, tau, wbuf1, b1l, h1, h1f8, ntiles);
    k_aggrb2  <<<ablocks, AB2, 0, stream>>>(binned, nodeoff, h1f8, zm2, N);
    k_gemm2   <<<gblocks, 256, 0, stream>>>(zm2, h1, wbuf2, b2l, Wfc, bfc, out, ntiles);
}